// Round 3
// baseline (7634.377 us; speedup 1.0000x reference)
//
#include <hip/hip_runtime.h>
#include <cstdint>
#include <cstddef>

constexpr int Bg = 64;     // graphs
constexpr int Nn = 1024;   // nodes per graph
constexpr int Kk = 10;     // kNN neighbors
constexpr int BN = Bg * Nn;
#define SLOPE 0.01f

__device__ __forceinline__ float lrelu(float v) { return v >= 0.f ? v : SLOPE * v; }

// order-preserving float -> uint encoding for atomicMax
__device__ __forceinline__ unsigned encf(float f) {
  unsigned u = __float_as_uint(f);
  return (u & 0x80000000u) ? ~u : (u | 0x80000000u);
}
__device__ __forceinline__ float decf(unsigned e) {
  unsigned u = (e & 0x80000000u) ? (e & 0x7fffffffu) : ~e;
  return __uint_as_float(u);
}

__global__ __launch_bounds__(256) void pooled_init(unsigned* __restrict__ p) {
  p[blockIdx.x * 256 + threadIdx.x] = 0u;
}

// ---------------- build xx = [tq, x, pos] (chunk-local rows, global inputs) ----------------
__global__ __launch_bounds__(256) void build_xx(const float* __restrict__ x,
                                                const float* __restrict__ pos,
                                                const float* __restrict__ tq,
                                                float* __restrict__ xx, int rowoff) {
  int n = blockIdx.x * 256 + threadIdx.x;
  int g = rowoff + n;
  xx[n * 5 + 0] = tq[g];
  xx[n * 5 + 1] = x[g];
  xx[n * 5 + 2] = pos[g * 3 + 0];
  xx[n * 5 + 3] = pos[g * 3 + 1];
  xx[n * 5 + 4] = pos[g * 3 + 2];
}

// ---------------- U = h @ (Wt - Wb), V = h @ Wb ----------------
template <int F>
__global__ __launch_bounds__(256) void uv_kernel(const float* __restrict__ h,
                                                 const float* __restrict__ W,  // [2F][64]
                                                 float* __restrict__ U,
                                                 float* __restrict__ V) {
  __shared__ float Ws[2 * F * 64];
  __shared__ float hs[16 * F];
  const int t = threadIdx.x;
  const int n0 = blockIdx.x * 16;
  for (int l = t; l < 2 * F * 64; l += 256) Ws[l] = W[l];
  for (int l = t; l < 16 * F; l += 256) hs[l] = h[(size_t)n0 * F + l];
  __syncthreads();
  for (int l = t; l < F * 64; l += 256) Ws[l] = Ws[l] - Ws[F * 64 + l];
  __syncthreads();
  const int o = t & 63;
  #pragma unroll
  for (int g4 = 0; g4 < 16; g4 += 4) {
    const int g = g4 + (t >> 6);
    float u = 0.f, v = 0.f;
    for (int f = 0; f < F; ++f) {
      float hv = hs[g * F + f];
      u += hv * Ws[f * 64 + o];
      v += hv * Ws[F * 64 + f * 64 + o];
    }
    U[(size_t)(n0 + g) * 64 + o] = u;
    V[(size_t)(n0 + g) * 64 + o] = v;
  }
}

// ---------------- sq[n] = sum_f h[n][f]^2 ----------------
template <int F>
__global__ __launch_bounds__(256) void sq_kernel(const float* __restrict__ h,
                                                 float* __restrict__ sqn) {
  int n = blockIdx.x * 4 + (threadIdx.x >> 6);
  int f = threadIdx.x & 63;
  float v = 0.f;
  if (f < F) v = h[(size_t)n * F + f];
  v *= v;
  #pragma unroll
  for (int off = 32; off > 0; off >>= 1) v += __shfl_down(v, off, 64);
  if (f == 0) sqn[n] = v;
}

// ---------------- kNN v2: 64 i-rows/block, 4 threads per row ----------------
// dist(i,j) = sq_j - 2*hi.hj  (same ordering as ref's sq_i+sq_j-2dot)
template <int F>
__global__ __launch_bounds__(256) void knn_kernel(const float* __restrict__ h,
                                                  const float* __restrict__ sqn,
                                                  int* __restrict__ idxout) {
  constexpr int TJ = 128;
  constexpr int IPB = 64;
  constexpr int PADF = ((F & 31) == 0) ? F + 4 : F;   // break stride-64 banks
  constexpr int TILE_F = TJ * PADF;
  constexpr int MERGE_F = IPB * 40 * 2;                // (d,idx) x 40 per row
  constexpr int UNI_F = TILE_F > MERGE_F ? TILE_F : MERGE_F;
  __shared__ float uni[UNI_F];
  __shared__ float sqt[TJ];
  float* tile = uni;
  float* md = uni;                    // merge dists  [IPB*40]
  int*   mi = (int*)(uni + IPB * 40); // merge idxs   [IPB*40]

  const int b = blockIdx.y;
  const int i0 = blockIdx.x * IPB;
  const int t = threadIdx.x;
  const int r = t >> 2;   // local i-row
  const int s = t & 3;    // j-subset
  const int gbase = b * Nn;
  const int irow = gbase + i0 + r;

  float hi[F];
  if constexpr ((F & 3) == 0) {
    #pragma unroll
    for (int f4 = 0; f4 < F / 4; ++f4) {
      float4 v = *(const float4*)&h[(size_t)irow * F + f4 * 4];
      hi[f4 * 4 + 0] = v.x; hi[f4 * 4 + 1] = v.y;
      hi[f4 * 4 + 2] = v.z; hi[f4 * 4 + 3] = v.w;
    }
  } else {
    #pragma unroll
    for (int f = 0; f < F; ++f) hi[f] = h[(size_t)irow * F + f];
  }

  float bd[Kk];
  int bi[Kk];
  #pragma unroll
  for (int q = 0; q < Kk; ++q) { bd[q] = INFINITY; bi[q] = 0x7fffffff; }
  float cm = INFINITY;
  int cmi = 0x7fffffff;
  int mp = 0;

  auto insert = [&](float d, int j) {
    if (d < cm) {
      #pragma unroll
      for (int q = 0; q < Kk; ++q) {
        if (q == mp) { bd[q] = d; bi[q] = j; }
      }
      cm = -INFINITY; cmi = -1; mp = 0;
      #pragma unroll
      for (int q = 0; q < Kk; ++q) {
        bool g = (bd[q] > cm) || (bd[q] == cm && bi[q] > cmi);
        if (g) { cm = bd[q]; cmi = bi[q]; mp = q; }
      }
    }
  };

  for (int jt = 0; jt < Nn; jt += TJ) {
    __syncthreads();
    if constexpr ((F & 3) == 0) {
      for (int l4 = t; l4 < TJ * (F / 4); l4 += 256) {
        int j = l4 / (F / 4), f4 = l4 % (F / 4);
        float4 v = *(const float4*)&h[(size_t)(gbase + jt + j) * F + f4 * 4];
        *(float4*)(tile + j * PADF + f4 * 4) = v;
      }
    } else {
      for (int l = t; l < TJ * F; l += 256) {
        int j = l / F, f = l % F;
        tile[j * PADF + f] = h[(size_t)(gbase + jt + j) * F + f];
      }
    }
    if (t < TJ) sqt[t] = sqn[gbase + jt + t];
    __syncthreads();
    // this thread's 32 js: groups of 4 consecutive at j0 = s*4 + k*16
    #pragma unroll 1
    for (int k = 0; k < TJ / 16; ++k) {
      const int j0 = s * 4 + k * 16;
      float dot0 = 0.f, dot1 = 0.f, dot2 = 0.f, dot3 = 0.f;
      if constexpr ((F & 3) == 0) {
        #pragma unroll
        for (int f4 = 0; f4 < F / 4; ++f4) {
          float4 t0 = *(const float4*)(tile + (j0 + 0) * PADF + f4 * 4);
          float4 t1 = *(const float4*)(tile + (j0 + 1) * PADF + f4 * 4);
          float4 t2 = *(const float4*)(tile + (j0 + 2) * PADF + f4 * 4);
          float4 t3 = *(const float4*)(tile + (j0 + 3) * PADF + f4 * 4);
          float a0 = hi[f4 * 4 + 0], a1 = hi[f4 * 4 + 1], a2 = hi[f4 * 4 + 2], a3 = hi[f4 * 4 + 3];
          dot0 += a0 * t0.x + a1 * t0.y + a2 * t0.z + a3 * t0.w;
          dot1 += a0 * t1.x + a1 * t1.y + a2 * t1.z + a3 * t1.w;
          dot2 += a0 * t2.x + a1 * t2.y + a2 * t2.z + a3 * t2.w;
          dot3 += a0 * t3.x + a1 * t3.y + a2 * t3.z + a3 * t3.w;
        }
      } else {
        #pragma unroll
        for (int f = 0; f < F; ++f) {
          float a = hi[f];
          dot0 += a * tile[(j0 + 0) * PADF + f];
          dot1 += a * tile[(j0 + 1) * PADF + f];
          dot2 += a * tile[(j0 + 2) * PADF + f];
          dot3 += a * tile[(j0 + 3) * PADF + f];
        }
      }
      insert(sqt[j0 + 0] - 2.f * dot0, jt + j0 + 0);
      insert(sqt[j0 + 1] - 2.f * dot1, jt + j0 + 1);
      insert(sqt[j0 + 2] - 2.f * dot2, jt + j0 + 2);
      insert(sqt[j0 + 3] - 2.f * dot3, jt + j0 + 3);
    }
  }

  // merge 4 partial top-10s per row -> top-10
  __syncthreads();
  #pragma unroll
  for (int q = 0; q < Kk; ++q) {
    md[r * 40 + s * 10 + q] = bd[q];
    mi[r * 40 + s * 10 + q] = bi[q];
  }
  __syncthreads();
  if (s == 0) {
    float* rd = md + r * 40;
    int*   ri = mi + r * 40;
    #pragma unroll 1
    for (int q = 0; q < Kk; ++q) {
      float best = INFINITY;
      int besti = 0x7fffffff, bslot = 0;
      #pragma unroll 1
      for (int e = 0; e < 40; ++e) {
        float d = rd[e];
        int ix = ri[e];
        bool g = (d < best) || (d == best && ix < besti);
        if (g) { best = d; besti = ix; bslot = e; }
      }
      rd[bslot] = INFINITY;
      idxout[(size_t)irow * Kk + q] = besti;
    }
  }
}

// ---------------- h_out[i] = sum_k lrelu(U[i] + V[j_k] + b) ----------------
__global__ __launch_bounds__(256) void agg_kernel(const float* __restrict__ U,
                                                  const float* __restrict__ V,
                                                  const int* __restrict__ idx,
                                                  const float* __restrict__ bias,
                                                  float* __restrict__ hout) {
  int t = blockIdx.x * 256 + threadIdx.x;
  int n = t >> 2;
  int o0 = (t & 3) * 16;
  int gb = n & ~(Nn - 1);
  float4 u[4], bb[4], acc[4];
  #pragma unroll
  for (int q = 0; q < 4; ++q) {
    u[q] = *(const float4*)&U[(size_t)n * 64 + o0 + q * 4];
    bb[q] = *(const float4*)&bias[o0 + q * 4];
    acc[q] = make_float4(0.f, 0.f, 0.f, 0.f);
  }
  #pragma unroll
  for (int k = 0; k < Kk; ++k) {
    int j = gb + idx[n * Kk + k];
    #pragma unroll
    for (int q = 0; q < 4; ++q) {
      float4 v = *(const float4*)&V[(size_t)j * 64 + o0 + q * 4];
      acc[q].x += lrelu(u[q].x + v.x + bb[q].x);
      acc[q].y += lrelu(u[q].y + v.y + bb[q].y);
      acc[q].z += lrelu(u[q].z + v.z + bb[q].z);
      acc[q].w += lrelu(u[q].w + v.w + bb[q].w);
    }
  }
  #pragma unroll
  for (int q = 0; q < 4; ++q)
    *(float4*)&hout[(size_t)n * 64 + o0 + q * 4] = acc[q];
}

// ---------------- fp32 GEMM 128x128 tile, 8x8/thread ----------------
// MODE 0: A = hc (6 slots of [Msl][64], K=384), rows zc+m0.. ; out = lrelu(acc+bias) -> z (rows m0..)
// MODE 1: A = z [Mz][512] (K=512), fused maxpool -> atomicMax(pooled[g0 + (zc+m0)>>10])
template <int MODE>
__global__ __launch_bounds__(256) void gemm_kernel(const float* __restrict__ A,
                                                   const float* __restrict__ Bw,
                                                   const float* __restrict__ bias,
                                                   float* __restrict__ outp,
                                                   unsigned* __restrict__ pooled,
                                                   int Msl, int zc, int g0) {
  constexpr int Kdim = (MODE == 0) ? 384 : 512;
  __shared__ float As[8][128];
  __shared__ float Bs[8][128];
  __shared__ float red[16][128];
  const int m0 = blockIdx.y * 128;
  const int n0 = blockIdx.x * 128;
  const int t = threadIdx.x;
  const int tx = t & 15, ty = t >> 4;

  float acc[8][8];
  #pragma unroll
  for (int i = 0; i < 8; ++i)
    #pragma unroll
    for (int j = 0; j < 8; ++j) acc[i][j] = 0.f;

  for (int k0 = 0; k0 < Kdim; k0 += 8) {
    float4 av, bv;
    {
      int am = m0 + (t >> 1);
      int ak = k0 + (t & 1) * 4;
      const float* ap;
      if (MODE == 0)
        ap = A + ((size_t)(ak >> 6) * Msl + zc + am) * 64 + (ak & 63);
      else
        ap = A + (size_t)am * 512 + ak;
      av = *(const float4*)ap;
      bv = *(const float4*)(Bw + (size_t)(k0 + (t >> 5)) * 512 + n0 + (t & 31) * 4);
    }
    __syncthreads();
    {
      int am = t >> 1, ak = (t & 1) * 4;
      As[ak + 0][am] = av.x;
      As[ak + 1][am] = av.y;
      As[ak + 2][am] = av.z;
      As[ak + 3][am] = av.w;
      *(float4*)&Bs[t >> 5][(t & 31) * 4] = bv;
    }
    __syncthreads();
    #pragma unroll
    for (int kk = 0; kk < 8; ++kk) {
      float4 a0 = *(const float4*)&As[kk][ty * 4];
      float4 a1 = *(const float4*)&As[kk][64 + ty * 4];
      float4 b0 = *(const float4*)&Bs[kk][tx * 4];
      float4 b1 = *(const float4*)&Bs[kk][64 + tx * 4];
      float ar[8] = {a0.x, a0.y, a0.z, a0.w, a1.x, a1.y, a1.z, a1.w};
      float br[8] = {b0.x, b0.y, b0.z, b0.w, b1.x, b1.y, b1.z, b1.w};
      #pragma unroll
      for (int i = 0; i < 8; ++i)
        #pragma unroll
        for (int j = 0; j < 8; ++j) acc[i][j] += ar[i] * br[j];
    }
  }

  if (MODE == 0) {
    #pragma unroll
    for (int i = 0; i < 8; ++i) {
      int row = m0 + ((i < 4) ? (ty * 4 + i) : (64 + ty * 4 + i - 4));
      #pragma unroll
      for (int jh = 0; jh < 2; ++jh) {
        int col = n0 + jh * 64 + tx * 4;
        float4 o;
        o.x = lrelu(acc[i][jh * 4 + 0] + bias[col + 0]);
        o.y = lrelu(acc[i][jh * 4 + 1] + bias[col + 1]);
        o.z = lrelu(acc[i][jh * 4 + 2] + bias[col + 2]);
        o.w = lrelu(acc[i][jh * 4 + 3] + bias[col + 3]);
        *(float4*)&outp[(size_t)row * 512 + col] = o;
      }
    }
  } else {
    float cmax[8];
    #pragma unroll
    for (int j = 0; j < 8; ++j) {
      float m = acc[0][j];
      #pragma unroll
      for (int i = 1; i < 8; ++i) m = fmaxf(m, acc[i][j]);
      cmax[j] = m;
    }
    __syncthreads();
    #pragma unroll
    for (int j = 0; j < 8; ++j) {
      int lc = ((j >= 4) ? 64 : 0) + tx * 4 + (j & 3);
      red[ty][lc] = cmax[j];
    }
    __syncthreads();
    if (t < 128) {
      float m = red[0][t];
      #pragma unroll
      for (int r = 1; r < 16; ++r) m = fmaxf(m, red[r][t]);
      m += bias[n0 + t];
      int b = g0 + ((zc + m0) >> 10);
      atomicMax(&pooled[(size_t)b * 512 + n0 + t], encf(m));
    }
  }
}

// ---------------- head: per graph, lrelu(pooled@Wm1+bm1)@Wm2+bm2 ----------------
__global__ __launch_bounds__(256) void head_kernel(const unsigned* __restrict__ pooled,
                                                   const float* __restrict__ Wm1,
                                                   const float* __restrict__ bm1,
                                                   const float* __restrict__ Wm2,
                                                   const float* __restrict__ bm2,
                                                   float* __restrict__ out) {
  __shared__ float ps[512];
  __shared__ float hs[256];
  int b = blockIdx.x;
  int t = threadIdx.x;
  for (int l = t; l < 512; l += 256) ps[l] = decf(pooled[(size_t)b * 512 + l]);
  __syncthreads();
  float acc = bm1[t];
  for (int f = 0; f < 512; ++f) acc += ps[f] * Wm1[f * 256 + t];
  hs[t] = lrelu(acc);
  __syncthreads();
  if (t < 3) {
    float y = bm2[t];
    for (int f = 0; f < 256; ++f) y += hs[f] * Wm2[f * 3 + t];
    out[b * 3 + t] = y;
  }
}

static inline size_t al256(size_t v) { return (v + 255) & ~(size_t)255; }

extern "C" void kernel_launch(void* const* d_in, const int* in_sizes, int n_in,
                              void* d_out, int out_size, void* d_ws, size_t ws_size,
                              hipStream_t stream) {
  (void)in_sizes; (void)n_in; (void)out_size;
  const float* x    = (const float*)d_in[0];
  const float* pos  = (const float*)d_in[1];
  const float* tq   = (const float*)d_in[2];
  // d_in[3] = batch (uniform & sorted; unused)
  const float* W1   = (const float*)d_in[4];
  const float* b1   = (const float*)d_in[5];
  const float* W2   = (const float*)d_in[6];
  const float* b2   = (const float*)d_in[7];
  const float* Wl1a = (const float*)d_in[8];
  const float* bl1a = (const float*)d_in[9];
  const float* Wl1b = (const float*)d_in[10];
  const float* bl1b = (const float*)d_in[11];
  const float* Wm1  = (const float*)d_in[12];
  const float* bm1  = (const float*)d_in[13];
  const float* Wm2  = (const float*)d_in[14];
  const float* bm2  = (const float*)d_in[15];
  float* out = (float*)d_out;

  // ---- pick largest graph-chunk G whose workspace fits in ws_size ----
  auto calc = [&](int G, size_t& hcB, size_t& uniB) -> size_t {
    size_t M = (size_t)G * Nn;
    hcB = al256(M * 384 * 4);                        // 6 x [M][64] fp32
    size_t convS = al256(M * 5 * 4) + 2 * al256(M * 64 * 4) +
                   al256(M * 4) + al256(M * Kk * 4); // xx,U,V,sqn,idx
    size_t Mz = M < 8192 ? M : 8192;
    size_t zB = al256(Mz * 512 * 4);
    uniB = convS > zB ? convS : zB;
    return hcB + uniB + al256((size_t)Bg * 512 * 4) + 1024;
  };
  int G = 64;
  size_t hcB = 0, uniB = 0;
  while (G > 1 && calc(G, hcB, uniB) > ws_size) G >>= 1;
  calc(G, hcB, uniB);
  const int M = G * Nn;
  const int Mz = M < 8192 ? M : 8192;

  char* w = (char*)d_ws;
  float*    hc  = (float*)w;
  char*     uni = w + hcB;
  float*    xx  = (float*)uni;
  float*    U   = (float*)(uni + al256((size_t)M * 5 * 4));
  float*    V   = (float*)((char*)U + al256((size_t)M * 64 * 4));
  float*    sqn = (float*)((char*)V + al256((size_t)M * 64 * 4));
  int*      idx = (int*)((char*)sqn + al256((size_t)M * 4));
  float*    z   = (float*)uni;  // MLP phase aliases conv scratch
  unsigned* pooled = (unsigned*)(w + hcB + uniB);

  pooled_init<<<(Bg * 512) / 256, 256, 0, stream>>>(pooled);

  for (int g0 = 0; g0 < Bg; g0 += G) {
    build_xx<<<M / 256, 256, 0, stream>>>(x, pos, tq, xx, g0 * Nn);

    // conv1 (F=5, W1) -> hc slot 0
    uv_kernel<5><<<M / 16, 256, 0, stream>>>(xx, W1, U, V);
    sq_kernel<5><<<M / 4, 256, 0, stream>>>(xx, sqn);
    knn_kernel<5><<<dim3(Nn / 64, G), 256, 0, stream>>>(xx, sqn, idx);
    agg_kernel<<<(size_t)M * 4 / 256, 256, 0, stream>>>(U, V, idx, b1, hc);

    // conv2..6 (F=64, shared W2) -> hc slots 1..5
    for (int c = 1; c < 6; ++c) {
      const float* hin = hc + (size_t)(c - 1) * M * 64;
      uv_kernel<64><<<M / 16, 256, 0, stream>>>(hin, W2, U, V);
      sq_kernel<64><<<M / 4, 256, 0, stream>>>(hin, sqn);
      knn_kernel<64><<<dim3(Nn / 64, G), 256, 0, stream>>>(hin, sqn, idx);
      agg_kernel<<<(size_t)M * 4 / 256, 256, 0, stream>>>(U, V, idx, b2,
                                                          hc + (size_t)c * M * 64);
    }

    // MLP over this chunk's rows, z-chunked
    for (int zc = 0; zc < M; zc += Mz) {
      gemm_kernel<0><<<dim3(4, Mz / 128), 256, 0, stream>>>(hc, Wl1a, bl1a, z, nullptr, M, zc, 0);
      gemm_kernel<1><<<dim3(4, Mz / 128), 256, 0, stream>>>(z, Wl1b, bl1b, nullptr, pooled, 0, zc, g0);
    }
  }

  head_kernel<<<Bg, 256, 0, stream>>>(pooled, Wm1, bm1, Wm2, bm2, out);
}

// Round 4
// 4030.934 us; speedup vs baseline: 1.8939x; 1.8939x over previous
//
#include <hip/hip_runtime.h>
#include <cstdint>
#include <cstddef>

constexpr int Bg = 64;     // graphs
constexpr int Nn = 1024;   // nodes per graph
constexpr int Kk = 10;     // kNN neighbors
constexpr int BN = Bg * Nn;
#define SLOPE 0.01f

__device__ __forceinline__ float lrelu(float v) { return v >= 0.f ? v : SLOPE * v; }

// order-preserving float -> uint encoding for atomicMax
__device__ __forceinline__ unsigned encf(float f) {
  unsigned u = __float_as_uint(f);
  return (u & 0x80000000u) ? ~u : (u | 0x80000000u);
}
__device__ __forceinline__ float decf(unsigned e) {
  unsigned u = (e & 0x80000000u) ? (e & 0x7fffffffu) : ~e;
  return __uint_as_float(u);
}

__global__ __launch_bounds__(256) void pooled_init(unsigned* __restrict__ p) {
  p[blockIdx.x * 256 + threadIdx.x] = 0u;
}

// ---------------- build xx = [tq, x, pos] (chunk-local rows, global inputs) ----------------
__global__ __launch_bounds__(256) void build_xx(const float* __restrict__ x,
                                                const float* __restrict__ pos,
                                                const float* __restrict__ tq,
                                                float* __restrict__ xx, int rowoff) {
  int n = blockIdx.x * 256 + threadIdx.x;
  int g = rowoff + n;
  xx[n * 5 + 0] = tq[g];
  xx[n * 5 + 1] = x[g];
  xx[n * 5 + 2] = pos[g * 3 + 0];
  xx[n * 5 + 3] = pos[g * 3 + 1];
  xx[n * 5 + 4] = pos[g * 3 + 2];
}

// ---------------- U = h @ (Wt - Wb), V = h @ Wb ----------------
template <int F>
__global__ __launch_bounds__(256) void uv_kernel(const float* __restrict__ h,
                                                 const float* __restrict__ W,  // [2F][64]
                                                 float* __restrict__ U,
                                                 float* __restrict__ V) {
  __shared__ float Ws[2 * F * 64];
  __shared__ float hs[16 * F];
  const int t = threadIdx.x;
  const int n0 = blockIdx.x * 16;
  for (int l = t; l < 2 * F * 64; l += 256) Ws[l] = W[l];
  for (int l = t; l < 16 * F; l += 256) hs[l] = h[(size_t)n0 * F + l];
  __syncthreads();
  for (int l = t; l < F * 64; l += 256) Ws[l] = Ws[l] - Ws[F * 64 + l];
  __syncthreads();
  const int o = t & 63;
  #pragma unroll
  for (int g4 = 0; g4 < 16; g4 += 4) {
    const int g = g4 + (t >> 6);
    float u = 0.f, v = 0.f;
    for (int f = 0; f < F; ++f) {
      float hv = hs[g * F + f];
      u += hv * Ws[f * 64 + o];
      v += hv * Ws[F * 64 + f * 64 + o];
    }
    U[(size_t)(n0 + g) * 64 + o] = u;
    V[(size_t)(n0 + g) * 64 + o] = v;
  }
}

// ---------------- sq[n] = sum_f h[n][f]^2 ----------------
template <int F>
__global__ __launch_bounds__(256) void sq_kernel(const float* __restrict__ h,
                                                 float* __restrict__ sqn) {
  int n = blockIdx.x * 4 + (threadIdx.x >> 6);
  int f = threadIdx.x & 63;
  float v = 0.f;
  if (f < F) v = h[(size_t)n * F + f];
  v *= v;
  #pragma unroll
  for (int off = 32; off > 0; off >>= 1) v += __shfl_down(v, off, 64);
  if (f == 0) sqn[n] = v;
}

// ---------------- kNN v3: GEMM-structured distances ----------------
// Block: 64 i-rows of one graph. j-tiles of 64. Threads (tx,ty) 16x16,
// each computes acc[4i][4j] dot tile from LDS (As transposed [F][68],
// Bs transposed [F][68]). dist = sqt[j] - 2*dot (bit-identical fmac-chain
// in f-order to rounds 2/3 -> identical neighbor selection). D-tile in LDS
// (aliases dead Bs), then 4 threads/row streaming top-10 + 40->10 merge.
template <int F>
__global__ __launch_bounds__(256) void knn_kernel(const float* __restrict__ h,
                                                  const float* __restrict__ sqn,
                                                  int* __restrict__ idxout) {
  constexpr int IPB = 64;
  constexpr int TJ = 64;
  constexpr int LDA = IPB + 4;  // 68: breaks power-of-2 bank strides
  constexpr int UNI = (IPB * 40 * 2 > 64 * LDA) ? IPB * 40 * 2 : 64 * LDA;  // 5120
  __shared__ float As[F][LDA];
  __shared__ float uni[UNI];
  __shared__ float sqt[TJ];
  float* Bs = uni;                      // [F][LDA]
  float* D  = uni;                      // [IPB][LDA] (after Bs consumed)
  float* md = uni;                      // merge dists [IPB*40]
  int*   mi = (int*)(uni + IPB * 40);   // merge idxs  [IPB*40]

  const int b = blockIdx.y;
  const int i0 = blockIdx.x * IPB;
  const int t = threadIdx.x;
  const int tx = t & 15, ty = t >> 4;
  const int gbase = b * Nn;

  // ---- stage As = h[i0..i0+63][:] transposed (coalesced global reads) ----
  if constexpr (F == 64) {
    #pragma unroll
    for (int p = 0; p < 4; ++p) {
      int l4 = t + 256 * p;
      int row = l4 >> 4, f4 = l4 & 15;
      float4 v = *(const float4*)&h[(size_t)(gbase + i0 + row) * 64 + f4 * 4];
      As[f4 * 4 + 0][row] = v.x; As[f4 * 4 + 1][row] = v.y;
      As[f4 * 4 + 2][row] = v.z; As[f4 * 4 + 3][row] = v.w;
    }
  } else {
    for (int l = t; l < IPB * F; l += 256) {
      int row = l / F, f = l % F;
      As[f][row] = h[(size_t)(gbase + i0 + row) * F + f];
    }
  }

  float bd[Kk];
  int bi[Kk];
  #pragma unroll
  for (int q = 0; q < Kk; ++q) { bd[q] = INFINITY; bi[q] = 0x7fffffff; }
  float cm = INFINITY;
  int cmi = 0x7fffffff;
  int mp = 0;

  auto insert = [&](float d, int j) {
    if (d < cm) {
      #pragma unroll
      for (int q = 0; q < Kk; ++q) {
        if (q == mp) { bd[q] = d; bi[q] = j; }
      }
      cm = -INFINITY; cmi = -1; mp = 0;
      #pragma unroll
      for (int q = 0; q < Kk; ++q) {
        bool g = (bd[q] > cm) || (bd[q] == cm && bi[q] > cmi);
        if (g) { cm = bd[q]; cmi = bi[q]; mp = q; }
      }
    }
  };

  const int r = t >> 2;   // selection: local i-row
  const int s = t & 3;    // selection: j-subset

  for (int jt = 0; jt < Nn; jt += TJ) {
    __syncthreads();  // previous selection done reading D (aliases Bs)
    // ---- stage Bs = h[jt..jt+63][:] transposed + sqt ----
    if constexpr (F == 64) {
      #pragma unroll
      for (int p = 0; p < 4; ++p) {
        int l4 = t + 256 * p;
        int row = l4 >> 4, f4 = l4 & 15;
        float4 v = *(const float4*)&h[(size_t)(gbase + jt + row) * 64 + f4 * 4];
        Bs[(f4 * 4 + 0) * LDA + row] = v.x; Bs[(f4 * 4 + 1) * LDA + row] = v.y;
        Bs[(f4 * 4 + 2) * LDA + row] = v.z; Bs[(f4 * 4 + 3) * LDA + row] = v.w;
      }
    } else {
      for (int l = t; l < TJ * F; l += 256) {
        int row = l / F, f = l % F;
        Bs[f * LDA + row] = h[(size_t)(gbase + jt + row) * F + f];
      }
    }
    if (t < TJ) sqt[t] = sqn[gbase + jt + t];
    __syncthreads();

    // ---- register-tile GEMM: acc[4i][4j] ----
    float acc[4][4] = {{0.f, 0.f, 0.f, 0.f}, {0.f, 0.f, 0.f, 0.f},
                       {0.f, 0.f, 0.f, 0.f}, {0.f, 0.f, 0.f, 0.f}};
    #pragma unroll 4
    for (int f = 0; f < F; ++f) {
      float4 av = *(const float4*)&As[f][ty * 4];
      float4 bv = *(const float4*)(Bs + f * LDA + tx * 4);
      acc[0][0] += av.x * bv.x; acc[0][1] += av.x * bv.y;
      acc[0][2] += av.x * bv.z; acc[0][3] += av.x * bv.w;
      acc[1][0] += av.y * bv.x; acc[1][1] += av.y * bv.y;
      acc[1][2] += av.y * bv.z; acc[1][3] += av.y * bv.w;
      acc[2][0] += av.z * bv.x; acc[2][1] += av.z * bv.y;
      acc[2][2] += av.z * bv.z; acc[2][3] += av.z * bv.w;
      acc[3][0] += av.w * bv.x; acc[3][1] += av.w * bv.y;
      acc[3][2] += av.w * bv.z; acc[3][3] += av.w * bv.w;
    }
    __syncthreads();  // all Bs reads done before D overwrites (alias)

    float4 sj = *(const float4*)&sqt[tx * 4];
    #pragma unroll
    for (int ii = 0; ii < 4; ++ii) {
      float4 dv;
      dv.x = sj.x - 2.f * acc[ii][0];
      dv.y = sj.y - 2.f * acc[ii][1];
      dv.z = sj.z - 2.f * acc[ii][2];
      dv.w = sj.w - 2.f * acc[ii][3];
      *(float4*)(D + (ty * 4 + ii) * LDA + tx * 4) = dv;
    }
    __syncthreads();

    // ---- selection: thread (r,s) scans js s*16..s*16+15 of this tile ----
    for (int q = 0; q < 16; ++q) {
      int j = s * 16 + q;
      insert(D[r * LDA + j], jt + j);
    }
  }

  // ---- merge 4 partial top-10s per row -> top-10 ----
  __syncthreads();
  #pragma unroll
  for (int q = 0; q < Kk; ++q) {
    md[r * 40 + s * 10 + q] = bd[q];
    mi[r * 40 + s * 10 + q] = bi[q];
  }
  __syncthreads();
  if (s == 0) {
    float* rd = md + r * 40;
    int*   ri = mi + r * 40;
    #pragma unroll 1
    for (int q = 0; q < Kk; ++q) {
      float best = INFINITY;
      int besti = 0x7fffffff, bslot = 0;
      #pragma unroll 1
      for (int e = 0; e < 40; ++e) {
        float d = rd[e];
        int ix = ri[e];
        bool g = (d < best) || (d == best && ix < besti);
        if (g) { best = d; besti = ix; bslot = e; }
      }
      rd[bslot] = INFINITY;
      idxout[(size_t)(gbase + i0 + r) * Kk + q] = besti;
    }
  }
}

// ---------------- h_out[i] = sum_k lrelu(U[i] + V[j_k] + b) ----------------
__global__ __launch_bounds__(256) void agg_kernel(const float* __restrict__ U,
                                                  const float* __restrict__ V,
                                                  const int* __restrict__ idx,
                                                  const float* __restrict__ bias,
                                                  float* __restrict__ hout) {
  int t = blockIdx.x * 256 + threadIdx.x;
  int n = t >> 2;
  int o0 = (t & 3) * 16;
  int gb = n & ~(Nn - 1);
  float4 u[4], bb[4], acc[4];
  #pragma unroll
  for (int q = 0; q < 4; ++q) {
    u[q] = *(const float4*)&U[(size_t)n * 64 + o0 + q * 4];
    bb[q] = *(const float4*)&bias[o0 + q * 4];
    acc[q] = make_float4(0.f, 0.f, 0.f, 0.f);
  }
  #pragma unroll
  for (int k = 0; k < Kk; ++k) {
    int j = gb + idx[n * Kk + k];
    #pragma unroll
    for (int q = 0; q < 4; ++q) {
      float4 v = *(const float4*)&V[(size_t)j * 64 + o0 + q * 4];
      acc[q].x += lrelu(u[q].x + v.x + bb[q].x);
      acc[q].y += lrelu(u[q].y + v.y + bb[q].y);
      acc[q].z += lrelu(u[q].z + v.z + bb[q].z);
      acc[q].w += lrelu(u[q].w + v.w + bb[q].w);
    }
  }
  #pragma unroll
  for (int q = 0; q < 4; ++q)
    *(float4*)&hout[(size_t)n * 64 + o0 + q * 4] = acc[q];
}

// ---------------- fp32 GEMM 128x128 tile, 8x8/thread ----------------
// MODE 0: A = hc (6 slots of [Msl][64], K=384), rows zc+m0.. ; out = lrelu(acc+bias) -> z (rows m0..)
// MODE 1: A = z [Mz][512] (K=512), fused maxpool -> atomicMax(pooled[g0 + (zc+m0)>>10])
template <int MODE>
__global__ __launch_bounds__(256) void gemm_kernel(const float* __restrict__ A,
                                                   const float* __restrict__ Bw,
                                                   const float* __restrict__ bias,
                                                   float* __restrict__ outp,
                                                   unsigned* __restrict__ pooled,
                                                   int Msl, int zc, int g0) {
  constexpr int Kdim = (MODE == 0) ? 384 : 512;
  __shared__ float As[8][128];
  __shared__ float Bs[8][128];
  __shared__ float red[16][128];
  const int m0 = blockIdx.y * 128;
  const int n0 = blockIdx.x * 128;
  const int t = threadIdx.x;
  const int tx = t & 15, ty = t >> 4;

  float acc[8][8];
  #pragma unroll
  for (int i = 0; i < 8; ++i)
    #pragma unroll
    for (int j = 0; j < 8; ++j) acc[i][j] = 0.f;

  for (int k0 = 0; k0 < Kdim; k0 += 8) {
    float4 av, bv;
    {
      int am = m0 + (t >> 1);
      int ak = k0 + (t & 1) * 4;
      const float* ap;
      if (MODE == 0)
        ap = A + ((size_t)(ak >> 6) * Msl + zc + am) * 64 + (ak & 63);
      else
        ap = A + (size_t)am * 512 + ak;
      av = *(const float4*)ap;
      bv = *(const float4*)(Bw + (size_t)(k0 + (t >> 5)) * 512 + n0 + (t & 31) * 4);
    }
    __syncthreads();
    {
      int am = t >> 1, ak = (t & 1) * 4;
      As[ak + 0][am] = av.x;
      As[ak + 1][am] = av.y;
      As[ak + 2][am] = av.z;
      As[ak + 3][am] = av.w;
      *(float4*)&Bs[t >> 5][(t & 31) * 4] = bv;
    }
    __syncthreads();
    #pragma unroll
    for (int kk = 0; kk < 8; ++kk) {
      float4 a0 = *(const float4*)&As[kk][ty * 4];
      float4 a1 = *(const float4*)&As[kk][64 + ty * 4];
      float4 b0 = *(const float4*)&Bs[kk][tx * 4];
      float4 b1 = *(const float4*)&Bs[kk][64 + tx * 4];
      float ar[8] = {a0.x, a0.y, a0.z, a0.w, a1.x, a1.y, a1.z, a1.w};
      float br[8] = {b0.x, b0.y, b0.z, b0.w, b1.x, b1.y, b1.z, b1.w};
      #pragma unroll
      for (int i = 0; i < 8; ++i)
        #pragma unroll
        for (int j = 0; j < 8; ++j) acc[i][j] += ar[i] * br[j];
    }
  }

  if (MODE == 0) {
    #pragma unroll
    for (int i = 0; i < 8; ++i) {
      int row = m0 + ((i < 4) ? (ty * 4 + i) : (64 + ty * 4 + i - 4));
      #pragma unroll
      for (int jh = 0; jh < 2; ++jh) {
        int col = n0 + jh * 64 + tx * 4;
        float4 o;
        o.x = lrelu(acc[i][jh * 4 + 0] + bias[col + 0]);
        o.y = lrelu(acc[i][jh * 4 + 1] + bias[col + 1]);
        o.z = lrelu(acc[i][jh * 4 + 2] + bias[col + 2]);
        o.w = lrelu(acc[i][jh * 4 + 3] + bias[col + 3]);
        *(float4*)&outp[(size_t)row * 512 + col] = o;
      }
    }
  } else {
    float cmax[8];
    #pragma unroll
    for (int j = 0; j < 8; ++j) {
      float m = acc[0][j];
      #pragma unroll
      for (int i = 1; i < 8; ++i) m = fmaxf(m, acc[i][j]);
      cmax[j] = m;
    }
    __syncthreads();
    #pragma unroll
    for (int j = 0; j < 8; ++j) {
      int lc = ((j >= 4) ? 64 : 0) + tx * 4 + (j & 3);
      red[ty][lc] = cmax[j];
    }
    __syncthreads();
    if (t < 128) {
      float m = red[0][t];
      #pragma unroll
      for (int r = 1; r < 16; ++r) m = fmaxf(m, red[r][t]);
      m += bias[n0 + t];
      int b = g0 + ((zc + m0) >> 10);
      atomicMax(&pooled[(size_t)b * 512 + n0 + t], encf(m));
    }
  }
}

// ---------------- head: per graph, lrelu(pooled@Wm1+bm1)@Wm2+bm2 ----------------
__global__ __launch_bounds__(256) void head_kernel(const unsigned* __restrict__ pooled,
                                                   const float* __restrict__ Wm1,
                                                   const float* __restrict__ bm1,
                                                   const float* __restrict__ Wm2,
                                                   const float* __restrict__ bm2,
                                                   float* __restrict__ out) {
  __shared__ float ps[512];
  __shared__ float hs[256];
  int b = blockIdx.x;
  int t = threadIdx.x;
  for (int l = t; l < 512; l += 256) ps[l] = decf(pooled[(size_t)b * 512 + l]);
  __syncthreads();
  float acc = bm1[t];
  for (int f = 0; f < 512; ++f) acc += ps[f] * Wm1[f * 256 + t];
  hs[t] = lrelu(acc);
  __syncthreads();
  if (t < 3) {
    float y = bm2[t];
    for (int f = 0; f < 256; ++f) y += hs[f] * Wm2[f * 3 + t];
    out[b * 3 + t] = y;
  }
}

static inline size_t al256(size_t v) { return (v + 255) & ~(size_t)255; }

extern "C" void kernel_launch(void* const* d_in, const int* in_sizes, int n_in,
                              void* d_out, int out_size, void* d_ws, size_t ws_size,
                              hipStream_t stream) {
  (void)in_sizes; (void)n_in; (void)out_size;
  const float* x    = (const float*)d_in[0];
  const float* pos  = (const float*)d_in[1];
  const float* tq   = (const float*)d_in[2];
  // d_in[3] = batch (uniform & sorted; unused)
  const float* W1   = (const float*)d_in[4];
  const float* b1   = (const float*)d_in[5];
  const float* W2   = (const float*)d_in[6];
  const float* b2   = (const float*)d_in[7];
  const float* Wl1a = (const float*)d_in[8];
  const float* bl1a = (const float*)d_in[9];
  const float* Wl1b = (const float*)d_in[10];
  const float* bl1b = (const float*)d_in[11];
  const float* Wm1  = (const float*)d_in[12];
  const float* bm1  = (const float*)d_in[13];
  const float* Wm2  = (const float*)d_in[14];
  const float* bm2  = (const float*)d_in[15];
  float* out = (float*)d_out;

  // ---- pick largest graph-chunk G whose workspace fits in ws_size ----
  auto calc = [&](int G, size_t& hcB, size_t& uniB) -> size_t {
    size_t M = (size_t)G * Nn;
    hcB = al256(M * 384 * 4);                        // 6 x [M][64] fp32
    size_t convS = al256(M * 5 * 4) + 2 * al256(M * 64 * 4) +
                   al256(M * 4) + al256(M * Kk * 4); // xx,U,V,sqn,idx
    size_t Mz = M < 8192 ? M : 8192;
    size_t zB = al256(Mz * 512 * 4);
    uniB = convS > zB ? convS : zB;
    return hcB + uniB + al256((size_t)Bg * 512 * 4) + 1024;
  };
  int G = 64;
  size_t hcB = 0, uniB = 0;
  while (G > 1 && calc(G, hcB, uniB) > ws_size) G >>= 1;
  calc(G, hcB, uniB);
  const int M = G * Nn;
  const int Mz = M < 8192 ? M : 8192;

  char* w = (char*)d_ws;
  float*    hc  = (float*)w;
  char*     uni = w + hcB;
  float*    xx  = (float*)uni;
  float*    U   = (float*)(uni + al256((size_t)M * 5 * 4));
  float*    V   = (float*)((char*)U + al256((size_t)M * 64 * 4));
  float*    sqn = (float*)((char*)V + al256((size_t)M * 64 * 4));
  int*      idx = (int*)((char*)sqn + al256((size_t)M * 4));
  float*    z   = (float*)uni;  // MLP phase aliases conv scratch
  unsigned* pooled = (unsigned*)(w + hcB + uniB);

  pooled_init<<<(Bg * 512) / 256, 256, 0, stream>>>(pooled);

  for (int g0 = 0; g0 < Bg; g0 += G) {
    build_xx<<<M / 256, 256, 0, stream>>>(x, pos, tq, xx, g0 * Nn);

    // conv1 (F=5, W1) -> hc slot 0
    uv_kernel<5><<<M / 16, 256, 0, stream>>>(xx, W1, U, V);
    sq_kernel<5><<<M / 4, 256, 0, stream>>>(xx, sqn);
    knn_kernel<5><<<dim3(Nn / 64, G), 256, 0, stream>>>(xx, sqn, idx);
    agg_kernel<<<(size_t)M * 4 / 256, 256, 0, stream>>>(U, V, idx, b1, hc);

    // conv2..6 (F=64, shared W2) -> hc slots 1..5
    for (int c = 1; c < 6; ++c) {
      const float* hin = hc + (size_t)(c - 1) * M * 64;
      uv_kernel<64><<<M / 16, 256, 0, stream>>>(hin, W2, U, V);
      sq_kernel<64><<<M / 4, 256, 0, stream>>>(hin, sqn);
      knn_kernel<64><<<dim3(Nn / 64, G), 256, 0, stream>>>(hin, sqn, idx);
      agg_kernel<<<(size_t)M * 4 / 256, 256, 0, stream>>>(U, V, idx, b2,
                                                          hc + (size_t)c * M * 64);
    }

    // MLP over this chunk's rows, z-chunked
    for (int zc = 0; zc < M; zc += Mz) {
      gemm_kernel<0><<<dim3(4, Mz / 128), 256, 0, stream>>>(hc, Wl1a, bl1a, z, nullptr, M, zc, 0);
      gemm_kernel<1><<<dim3(4, Mz / 128), 256, 0, stream>>>(z, Wl1b, bl1b, nullptr, pooled, 0, zc, g0);
    }
  }

  head_kernel<<<Bg, 256, 0, stream>>>(pooled, Wm1, bm1, Wm2, bm2, out);
}

// Round 6
// 3230.796 us; speedup vs baseline: 2.3630x; 1.2477x over previous
//
#include <hip/hip_runtime.h>
#include <cstdint>
#include <cstddef>

constexpr int Bg = 64;     // graphs
constexpr int Nn = 1024;   // nodes per graph
constexpr int Kk = 10;     // kNN neighbors
constexpr int BN = Bg * Nn;
#define SLOPE 0.01f

typedef __attribute__((ext_vector_type(8))) short s16x8;
typedef __attribute__((ext_vector_type(4))) float f32x4;

__device__ __forceinline__ float lrelu(float v) { return v >= 0.f ? v : SLOPE * v; }

// order-preserving float -> uint encoding
__device__ __forceinline__ unsigned encf(float f) {
  unsigned u = __float_as_uint(f);
  return (u & 0x80000000u) ? ~u : (u | 0x80000000u);
}
__device__ __forceinline__ float decf(unsigned e) {
  unsigned u = (e & 0x80000000u) ? (e & 0x7fffffffu) : ~e;
  return __uint_as_float(u);
}
// f32 -> bf16 (RNE) and back
__device__ __forceinline__ unsigned short f2bf(float f) {
  unsigned u = __float_as_uint(f);
  return (unsigned short)((u + 0x7FFFu + ((u >> 16) & 1u)) >> 16);
}
__device__ __forceinline__ float bf2f(unsigned short h) {
  return __uint_as_float(((unsigned)h) << 16);
}

__device__ __forceinline__ f32x4 mfma16(s16x8 a, s16x8 b, f32x4 c) {
  return __builtin_amdgcn_mfma_f32_16x16x32_bf16(a, b, c, 0, 0, 0);
}

__global__ __launch_bounds__(256) void pooled_init(unsigned* __restrict__ p) {
  p[blockIdx.x * 256 + threadIdx.x] = 0u;
}

// ---------------- build xx = [tq, x, pos] ----------------
__global__ __launch_bounds__(256) void build_xx(const float* __restrict__ x,
                                                const float* __restrict__ pos,
                                                const float* __restrict__ tq,
                                                float* __restrict__ xx, int rowoff) {
  int n = blockIdx.x * 256 + threadIdx.x;
  int g = rowoff + n;
  xx[n * 5 + 0] = tq[g];
  xx[n * 5 + 1] = x[g];
  xx[n * 5 + 2] = pos[g * 3 + 0];
  xx[n * 5 + 3] = pos[g * 3 + 1];
  xx[n * 5 + 4] = pos[g * 3 + 2];
}

// ---------------- weight prep: W[K][512] f32 -> WH/WL [512][K] bf16 ----------------
template <int K>
__global__ __launch_bounds__(256) void wprep(const float* __restrict__ W,
                                             short* __restrict__ WH,
                                             short* __restrict__ WL) {
  int idx = blockIdx.x * 256 + threadIdx.x;
  int k = idx >> 9, n = idx & 511;
  float v = W[idx];
  unsigned short h = f2bf(v);
  unsigned short lo = f2bf(v - bf2f(h));
  WH[(size_t)n * K + k] = (short)h;
  WL[(size_t)n * K + k] = (short)lo;
}

// ---------------- U = h @ (Wt - Wb), V = h @ Wb ----------------
template <int F>
__global__ __launch_bounds__(256) void uv_kernel(const float* __restrict__ h,
                                                 const float* __restrict__ W,  // [2F][64]
                                                 float* __restrict__ U,
                                                 float* __restrict__ V) {
  __shared__ float Ws[2 * F * 64];
  __shared__ float hs[16 * F];
  const int t = threadIdx.x;
  const int n0 = blockIdx.x * 16;
  for (int l = t; l < 2 * F * 64; l += 256) Ws[l] = W[l];
  for (int l = t; l < 16 * F; l += 256) hs[l] = h[(size_t)n0 * F + l];
  __syncthreads();
  for (int l = t; l < F * 64; l += 256) Ws[l] = Ws[l] - Ws[F * 64 + l];
  __syncthreads();
  const int o = t & 63;
  #pragma unroll
  for (int g4 = 0; g4 < 16; g4 += 4) {
    const int g = g4 + (t >> 6);
    float u = 0.f, v = 0.f;
    for (int f = 0; f < F; ++f) {
      float hv = hs[g * F + f];
      u += hv * Ws[f * 64 + o];
      v += hv * Ws[F * 64 + f * 64 + o];
    }
    U[(size_t)(n0 + g) * 64 + o] = u;
    V[(size_t)(n0 + g) * 64 + o] = v;
  }
}

// ---------------- sq[n] = sum_f h[n][f]^2 ----------------
template <int F>
__global__ __launch_bounds__(256) void sq_kernel(const float* __restrict__ h,
                                                 float* __restrict__ sqn) {
  int n = blockIdx.x * 4 + (threadIdx.x >> 6);
  int f = threadIdx.x & 63;
  float v = 0.f;
  if (f < F) v = h[(size_t)n * F + f];
  v *= v;
  #pragma unroll
  for (int off = 32; off > 0; off >>= 1) v += __shfl_down(v, off, 64);
  if (f == 0) sqn[n] = v;
}

// ---------------- kNN v6: GEMM distances + exact (d,j)-lexicographic top-10 ----------------
template <int F>
__global__ __launch_bounds__(256) void knn_kernel(const float* __restrict__ h,
                                                  const float* __restrict__ sqn,
                                                  int* __restrict__ idxout) {
  constexpr int IPB = 64;
  constexpr int TJ = 64;
  constexpr int LDA = 68;   // floats; As/Bs pitch
  constexpr int LDD = 65;   // floats; D-tile pitch (conflict-free column reads)
  constexpr int LDM = 41;   // merge pitch (9 coprime 32 -> 2-way max)
  constexpr int UNI = (IPB * LDM * 2 > 64 * LDA) ? IPB * LDM * 2 : 64 * LDA;  // 5248
  __shared__ float As[F][LDA];
  __shared__ float uni[UNI];
  __shared__ float sqt[TJ];
  float* Bs = uni;                     // [F][LDA]
  float* D  = uni;                     // [IPB][LDD]
  float* md = uni;                     // merge dists [IPB][LDM]
  int*   mi = (int*)(uni + IPB * LDM); // merge idxs  [IPB][LDM]

  const int b = blockIdx.y;
  const int i0 = blockIdx.x * IPB;
  const int t = threadIdx.x;
  const int tx = t & 15, ty = t >> 4;
  const int gbase = b * Nn;
  const int r = t & 63;   // selection row
  const int s = t >> 6;   // selection j-subset (= wave id)

  // ---- stage As = h[i0..i0+63][:] transposed ----
  if constexpr (F == 64) {
    #pragma unroll
    for (int p = 0; p < 4; ++p) {
      int l4 = t + 256 * p;
      int row = l4 >> 4, f4 = l4 & 15;
      float4 v = *(const float4*)&h[(size_t)(gbase + i0 + row) * 64 + f4 * 4];
      As[f4 * 4 + 0][row] = v.x; As[f4 * 4 + 1][row] = v.y;
      As[f4 * 4 + 2][row] = v.z; As[f4 * 4 + 3][row] = v.w;
    }
  } else {
    for (int l = t; l < IPB * F; l += 256) {
      int row = l / F, f = l % F;
      As[f][row] = h[(size_t)(gbase + i0 + row) * F + f];
    }
  }

  // exact top-10 state (round-4 proven semantics)
  float bd[Kk];
  int bi[Kk];
  #pragma unroll
  for (int q = 0; q < Kk; ++q) { bd[q] = INFINITY; bi[q] = 0x7fffffff; }
  float cm = INFINITY;
  int cmi = 0x7fffffff;
  int mp = 0;

  auto insert = [&](float d, int j) {
    if (d < cm) {
      #pragma unroll
      for (int q = 0; q < Kk; ++q) {
        if (q == mp) { bd[q] = d; bi[q] = j; }
      }
      cm = -INFINITY; cmi = -1; mp = 0;
      #pragma unroll
      for (int q = 0; q < Kk; ++q) {
        bool g = (bd[q] > cm) || (bd[q] == cm && bi[q] > cmi);
        if (g) { cm = bd[q]; cmi = bi[q]; mp = q; }
      }
    }
  };

  for (int jt = 0; jt < Nn; jt += TJ) {
    __syncthreads();  // previous selection done reading D (aliases Bs)
    // ---- stage Bs = h[jt..jt+63][:] transposed + sqt ----
    if constexpr (F == 64) {
      #pragma unroll
      for (int p = 0; p < 4; ++p) {
        int l4 = t + 256 * p;
        int row = l4 >> 4, f4 = l4 & 15;
        float4 v = *(const float4*)&h[(size_t)(gbase + jt + row) * 64 + f4 * 4];
        Bs[(f4 * 4 + 0) * LDA + row] = v.x; Bs[(f4 * 4 + 1) * LDA + row] = v.y;
        Bs[(f4 * 4 + 2) * LDA + row] = v.z; Bs[(f4 * 4 + 3) * LDA + row] = v.w;
      }
    } else {
      for (int l = t; l < TJ * F; l += 256) {
        int row = l / F, f = l % F;
        Bs[f * LDA + row] = h[(size_t)(gbase + jt + row) * F + f];
      }
    }
    if (t < TJ) sqt[t] = sqn[gbase + jt + t];
    __syncthreads();

    // ---- register-tile GEMM: acc[4i][4j] ----
    float acc[4][4] = {{0.f, 0.f, 0.f, 0.f}, {0.f, 0.f, 0.f, 0.f},
                       {0.f, 0.f, 0.f, 0.f}, {0.f, 0.f, 0.f, 0.f}};
    #pragma unroll 8
    for (int f = 0; f < F; ++f) {
      float4 av = *(const float4*)&As[f][ty * 4];
      float4 bv = *(const float4*)(Bs + f * LDA + tx * 4);
      acc[0][0] += av.x * bv.x; acc[0][1] += av.x * bv.y;
      acc[0][2] += av.x * bv.z; acc[0][3] += av.x * bv.w;
      acc[1][0] += av.y * bv.x; acc[1][1] += av.y * bv.y;
      acc[1][2] += av.y * bv.z; acc[1][3] += av.y * bv.w;
      acc[2][0] += av.z * bv.x; acc[2][1] += av.z * bv.y;
      acc[2][2] += av.z * bv.z; acc[2][3] += av.z * bv.w;
      acc[3][0] += av.w * bv.x; acc[3][1] += av.w * bv.y;
      acc[3][2] += av.w * bv.z; acc[3][3] += av.w * bv.w;
    }
    __syncthreads();  // Bs consumed; D may overwrite

    // ---- store exact fp32 distances to D ----
    float4 sj = *(const float4*)&sqt[tx * 4];
    #pragma unroll
    for (int ii = 0; ii < 4; ++ii) {
      float* dr = D + (ty * 4 + ii) * LDD + tx * 4;
      dr[0] = sj.x - 2.f * acc[ii][0];
      dr[1] = sj.y - 2.f * acc[ii][1];
      dr[2] = sj.z - 2.f * acc[ii][2];
      dr[3] = sj.w - 2.f * acc[ii][3];
    }
    __syncthreads();

    // ---- selection: thread (r,s) scans js s*16..s*16+15 ascending ----
    #pragma unroll 1
    for (int qq = 0; qq < 16; ++qq) {
      int j = s * 16 + qq;
      insert(D[r * LDD + j], jt + j);
    }
  }

  // ---- merge 4 partial top-10s per row -> top-10 (lexicographic) ----
  __syncthreads();
  #pragma unroll
  for (int q = 0; q < Kk; ++q) {
    md[r * LDM + s * 10 + q] = bd[q];
    mi[r * LDM + s * 10 + q] = bi[q];
  }
  __syncthreads();
  if (s == 0) {
    float* rd = md + r * LDM;
    int*   ri = mi + r * LDM;
    #pragma unroll 1
    for (int q = 0; q < Kk; ++q) {
      float best = INFINITY;
      int besti = 0x7fffffff, bslot = 0;
      #pragma unroll 1
      for (int e = 0; e < 40; ++e) {
        float d = rd[e];
        int ix = ri[e];
        bool g = (d < best) || (d == best && ix < besti);
        if (g) { best = d; besti = ix; bslot = e; }
      }
      rd[bslot] = INFINITY;
      idxout[(size_t)(gbase + i0 + r) * Kk + q] = besti;
    }
  }
}

// ---------------- h_out[i] = sum_k lrelu(U[i] + V[j_k] + b); also bf16 hi/lo ----------------
__global__ __launch_bounds__(256) void agg_kernel(const float* __restrict__ U,
                                                  const float* __restrict__ V,
                                                  const int* __restrict__ idx,
                                                  const float* __restrict__ bias,
                                                  float* __restrict__ hout,
                                                  short* __restrict__ hH,
                                                  short* __restrict__ hL) {
  int t = blockIdx.x * 256 + threadIdx.x;
  int n = t >> 2;
  int o0 = (t & 3) * 16;
  int gb = n & ~(Nn - 1);
  float4 u[4], bb[4], acc[4];
  #pragma unroll
  for (int q = 0; q < 4; ++q) {
    u[q] = *(const float4*)&U[(size_t)n * 64 + o0 + q * 4];
    bb[q] = *(const float4*)&bias[o0 + q * 4];
    acc[q] = make_float4(0.f, 0.f, 0.f, 0.f);
  }
  #pragma unroll
  for (int k = 0; k < Kk; ++k) {
    int j = gb + idx[n * Kk + k];
    #pragma unroll
    for (int q = 0; q < 4; ++q) {
      float4 v = *(const float4*)&V[(size_t)j * 64 + o0 + q * 4];
      acc[q].x += lrelu(u[q].x + v.x + bb[q].x);
      acc[q].y += lrelu(u[q].y + v.y + bb[q].y);
      acc[q].z += lrelu(u[q].z + v.z + bb[q].z);
      acc[q].w += lrelu(u[q].w + v.w + bb[q].w);
    }
  }
  #pragma unroll
  for (int q = 0; q < 4; ++q) {
    *(float4*)&hout[(size_t)n * 64 + o0 + q * 4] = acc[q];
    ushort4 hv, lv;
    hv.x = f2bf(acc[q].x); lv.x = f2bf(acc[q].x - bf2f(hv.x));
    hv.y = f2bf(acc[q].y); lv.y = f2bf(acc[q].y - bf2f(hv.y));
    hv.z = f2bf(acc[q].z); lv.z = f2bf(acc[q].z - bf2f(hv.z));
    hv.w = f2bf(acc[q].w); lv.w = f2bf(acc[q].w - bf2f(hv.w));
    *(ushort4*)&hH[(size_t)n * 64 + o0 + q * 4] = hv;
    *(ushort4*)&hL[(size_t)n * 64 + o0 + q * 4] = lv;
  }
}

// ---------------- MFMA bf16x2 (hi/lo, 3-term) GEMM, 128x128 tile ----------------
// MODE 0: A = h (6 slots [Msl][64] bf16 pair), K=384 -> z = lrelu(A@B + bias) (bf16 pair, local rows)
// MODE 1: A = z ([Mz][512] bf16 pair), K=512 -> fused maxpool atomicMax(pooled)
// B operands pre-transposed [512][Kdim].
template <int MODE>
__global__ __launch_bounds__(256) void mfma_gemm(const short* __restrict__ AH,
                                                 const short* __restrict__ AL,
                                                 const short* __restrict__ BH,
                                                 const short* __restrict__ BL,
                                                 const float* __restrict__ bias,
                                                 short* __restrict__ outH,
                                                 short* __restrict__ outL,
                                                 unsigned* __restrict__ pooled,
                                                 int Msl, int zc, int g0) {
  constexpr int Kdim = (MODE == 0) ? 384 : 512;
  __shared__ short AHs[128][40], ALs[128][40], BHs[128][40], BLs[128][40];
  __shared__ float red[8][132];
  const int t = threadIdx.x;
  const int m0 = blockIdx.y * 128, n0 = blockIdx.x * 128;
  const int w = t >> 6, l = t & 63;
  const int q = w >> 1, p = w & 1, rl = l & 15, kb = l >> 4;
  const int srow = t >> 1, sc = (t & 1) * 16;

  f32x4 acc[4][4];
  #pragma unroll
  for (int m = 0; m < 4; ++m)
    #pragma unroll
    for (int n = 0; n < 4; ++n) acc[m][n] = (f32x4){0.f, 0.f, 0.f, 0.f};

  for (int k0 = 0; k0 < Kdim; k0 += 32) {
    size_t aoff, boff;
    if constexpr (MODE == 0)
      aoff = ((size_t)(k0 >> 6) * Msl + zc + m0 + srow) * 64 + (k0 & 63) + sc;
    else
      aoff = (size_t)(m0 + srow) * 512 + k0 + sc;
    boff = (size_t)(n0 + srow) * Kdim + k0 + sc;
    __syncthreads();
    *(uint4*)&AHs[srow][sc]     = *(const uint4*)(AH + aoff);
    *(uint4*)&AHs[srow][sc + 8] = *(const uint4*)(AH + aoff + 8);
    *(uint4*)&ALs[srow][sc]     = *(const uint4*)(AL + aoff);
    *(uint4*)&ALs[srow][sc + 8] = *(const uint4*)(AL + aoff + 8);
    *(uint4*)&BHs[srow][sc]     = *(const uint4*)(BH + boff);
    *(uint4*)&BHs[srow][sc + 8] = *(const uint4*)(BH + boff + 8);
    *(uint4*)&BLs[srow][sc]     = *(const uint4*)(BL + boff);
    *(uint4*)&BLs[srow][sc + 8] = *(const uint4*)(BL + boff + 8);
    __syncthreads();

    s16x8 aH[4], aL[4], bH[4], bL[4];
    #pragma unroll
    for (int m = 0; m < 4; ++m) {
      aH[m] = *(const s16x8*)&AHs[q * 64 + m * 16 + rl][kb * 8];
      aL[m] = *(const s16x8*)&ALs[q * 64 + m * 16 + rl][kb * 8];
    }
    #pragma unroll
    for (int n = 0; n < 4; ++n) {
      bH[n] = *(const s16x8*)&BHs[p * 64 + n * 16 + rl][kb * 8];
      bL[n] = *(const s16x8*)&BLs[p * 64 + n * 16 + rl][kb * 8];
    }
    #pragma unroll
    for (int m = 0; m < 4; ++m)
      #pragma unroll
      for (int n = 0; n < 4; ++n) {
        acc[m][n] = mfma16(aH[m], bH[n], acc[m][n]);
        acc[m][n] = mfma16(aH[m], bL[n], acc[m][n]);
        acc[m][n] = mfma16(aL[m], bH[n], acc[m][n]);
      }
  }

  if constexpr (MODE == 0) {
    #pragma unroll
    for (int n = 0; n < 4; ++n) {
      const int col = n0 + p * 64 + n * 16 + rl;
      const float bv = bias[col];
      #pragma unroll
      for (int m = 0; m < 4; ++m) {
        #pragma unroll
        for (int rr = 0; rr < 4; ++rr) {
          int row = m0 + q * 64 + m * 16 + kb * 4 + rr;
          float v = lrelu(acc[m][n][rr] + bv);
          unsigned short hv = f2bf(v);
          unsigned short lv = f2bf(v - bf2f(hv));
          outH[(size_t)row * 512 + col] = (short)hv;
          outL[(size_t)row * 512 + col] = (short)lv;
        }
      }
    }
  } else {
    #pragma unroll
    for (int n = 0; n < 4; ++n) {
      float cm = acc[0][n][0];
      #pragma unroll
      for (int m = 0; m < 4; ++m)
        #pragma unroll
        for (int rr = 0; rr < 4; ++rr) cm = fmaxf(cm, acc[m][n][rr]);
      red[q * 4 + kb][p * 64 + n * 16 + rl] = cm;
    }
    __syncthreads();
    if (t < 128) {
      float m = red[0][t];
      #pragma unroll
      for (int rr = 1; rr < 8; ++rr) m = fmaxf(m, red[rr][t]);
      m += bias[n0 + t];
      int g = g0 + ((zc + m0) >> 10);
      atomicMax(&pooled[(size_t)g * 512 + n0 + t], encf(m));
    }
  }
}

// ---------------- head: per graph, lrelu(pooled@Wm1+bm1)@Wm2+bm2 ----------------
__global__ __launch_bounds__(256) void head_kernel(const unsigned* __restrict__ pooled,
                                                   const float* __restrict__ Wm1,
                                                   const float* __restrict__ bm1,
                                                   const float* __restrict__ Wm2,
                                                   const float* __restrict__ bm2,
                                                   float* __restrict__ out) {
  __shared__ float ps[512];
  __shared__ float hs[256];
  int b = blockIdx.x;
  int t = threadIdx.x;
  for (int l = t; l < 512; l += 256) ps[l] = decf(pooled[(size_t)b * 512 + l]);
  __syncthreads();
  float acc = bm1[t];
  for (int f = 0; f < 512; ++f) acc += ps[f] * Wm1[f * 256 + t];
  hs[t] = lrelu(acc);
  __syncthreads();
  if (t < 3) {
    float y = bm2[t];
    for (int f = 0; f < 256; ++f) y += hs[f] * Wm2[f * 3 + t];
    out[b * 3 + t] = y;
  }
}

static inline size_t al256(size_t v) { return (v + 255) & ~(size_t)255; }

extern "C" void kernel_launch(void* const* d_in, const int* in_sizes, int n_in,
                              void* d_out, int out_size, void* d_ws, size_t ws_size,
                              hipStream_t stream) {
  (void)in_sizes; (void)n_in; (void)out_size;
  const float* x    = (const float*)d_in[0];
  const float* pos  = (const float*)d_in[1];
  const float* tq   = (const float*)d_in[2];
  // d_in[3] = batch (uniform & sorted; unused)
  const float* W1   = (const float*)d_in[4];
  const float* b1   = (const float*)d_in[5];
  const float* W2   = (const float*)d_in[6];
  const float* b2   = (const float*)d_in[7];
  const float* Wl1a = (const float*)d_in[8];
  const float* bl1a = (const float*)d_in[9];
  const float* Wl1b = (const float*)d_in[10];
  const float* bl1b = (const float*)d_in[11];
  const float* Wm1  = (const float*)d_in[12];
  const float* bm1  = (const float*)d_in[13];
  const float* Wm2  = (const float*)d_in[14];
  const float* bm2  = (const float*)d_in[15];
  float* out = (float*)d_out;

  // ---- pick largest graph-chunk G whose workspace fits ----
  auto calc = [&](int G, size_t& hcB, size_t& hHB, size_t& uniB, size_t& wB) -> size_t {
    size_t M = (size_t)G * Nn;
    hcB = al256(M * 384 * 4);        // f32 hc (6 slots [M][64])
    hHB = al256(M * 384 * 2);        // bf16 hi (and lo) copies
    size_t convS = al256(M * 5 * 4) + 2 * al256(M * 64 * 4) +
                   al256(M * 4) + al256(M * Kk * 4);
    size_t Mz = M < 16384 ? M : 16384;
    size_t zB = 2 * al256(Mz * 512 * 2);  // zH + zL bf16
    uniB = convS > zB ? convS : zB;
    wB = 2 * al256((size_t)512 * 384 * 2) + 2 * al256((size_t)512 * 512 * 2);
    return hcB + 2 * hHB + uniB + al256((size_t)Bg * 512 * 4) + wB + 1024;
  };
  int G = 64;
  size_t hcB = 0, hHB = 0, uniB = 0, wB = 0;
  while (G > 1 && calc(G, hcB, hHB, uniB, wB) > ws_size) G >>= 1;
  calc(G, hcB, hHB, uniB, wB);
  const int M = G * Nn;
  const int Mz = M < 16384 ? M : 16384;

  char* w = (char*)d_ws;
  float*    hc  = (float*)w;
  short*    hH  = (short*)(w + hcB);
  short*    hL  = (short*)(w + hcB + hHB);
  char*     uni = w + hcB + 2 * hHB;
  float*    xx  = (float*)uni;
  float*    U   = (float*)(uni + al256((size_t)M * 5 * 4));
  float*    V   = (float*)((char*)U + al256((size_t)M * 64 * 4));
  float*    sqn = (float*)((char*)V + al256((size_t)M * 64 * 4));
  int*      idx = (int*)((char*)sqn + al256((size_t)M * 4));
  short*    zH  = (short*)uni;                               // MLP phase aliases conv scratch
  short*    zL  = (short*)(uni + al256((size_t)Mz * 512 * 2));
  unsigned* pooled = (unsigned*)(uni + uniB);
  short*    WHa = (short*)((char*)pooled + al256((size_t)Bg * 512 * 4));
  short*    WLa = WHa + (size_t)512 * 384;
  short*    WHb = (short*)((char*)WHa + 2 * al256((size_t)512 * 384 * 2));
  short*    WLb = WHb + (size_t)512 * 512;

  wprep<384><<<(384 * 512) / 256, 256, 0, stream>>>(Wl1a, WHa, WLa);
  wprep<512><<<(512 * 512) / 256, 256, 0, stream>>>(Wl1b, WHb, WLb);
  pooled_init<<<(Bg * 512) / 256, 256, 0, stream>>>(pooled);

  for (int g0 = 0; g0 < Bg; g0 += G) {
    build_xx<<<M / 256, 256, 0, stream>>>(x, pos, tq, xx, g0 * Nn);

    // conv1 (F=5, W1) -> slot 0
    uv_kernel<5><<<M / 16, 256, 0, stream>>>(xx, W1, U, V);
    sq_kernel<5><<<M / 4, 256, 0, stream>>>(xx, sqn);
    knn_kernel<5><<<dim3(Nn / 64, G), 256, 0, stream>>>(xx, sqn, idx);
    agg_kernel<<<M / 64, 256, 0, stream>>>(U, V, idx, b1, hc, hH, hL);

    // conv2..6 (F=64, shared W2) -> slots 1..5
    for (int c = 1; c < 6; ++c) {
      const float* hin = hc + (size_t)(c - 1) * M * 64;
      uv_kernel<64><<<M / 16, 256, 0, stream>>>(hin, W2, U, V);
      sq_kernel<64><<<M / 4, 256, 0, stream>>>(hin, sqn);
      knn_kernel<64><<<dim3(Nn / 64, G), 256, 0, stream>>>(hin, sqn, idx);
      agg_kernel<<<M / 64, 256, 0, stream>>>(U, V, idx, b2,
                                             hc + (size_t)c * M * 64,
                                             hH + (size_t)c * M * 64,
                                             hL + (size_t)c * M * 64);
    }

    // MLP over this chunk's rows, z-chunked
    for (int zc = 0; zc < M; zc += Mz) {
      mfma_gemm<0><<<dim3(4, Mz / 128), 256, 0, stream>>>(hH, hL, WHa, WLa, bl1a,
                                                          zH, zL, nullptr, M, zc, 0);
      mfma_gemm<1><<<dim3(4, Mz / 128), 256, 0, stream>>>(zH, zL, WHb, WLb, bl1b,
                                                          nullptr, nullptr, pooled, Mz, zc, g0);
    }
  }

  head_kernel<<<Bg, 256, 0, stream>>>(pooled, Wm1, bm1, Wm2, bm2, out);
}

// Round 7
// 2997.388 us; speedup vs baseline: 2.5470x; 1.0779x over previous
//
#include <hip/hip_runtime.h>
#include <cstdint>
#include <cstddef>

constexpr int Bg = 64;     // graphs
constexpr int Nn = 1024;   // nodes per graph
constexpr int Kk = 10;     // kNN neighbors
constexpr int BN = Bg * Nn;
#define SLOPE 0.01f

typedef __attribute__((ext_vector_type(8))) short s16x8;
typedef __attribute__((ext_vector_type(4))) float f32x4;

__device__ __forceinline__ float lrelu(float v) { return v >= 0.f ? v : SLOPE * v; }

// order-preserving float -> uint encoding
__device__ __forceinline__ unsigned encf(float f) {
  unsigned u = __float_as_uint(f);
  return (u & 0x80000000u) ? ~u : (u | 0x80000000u);
}
__device__ __forceinline__ float decf(unsigned e) {
  unsigned u = (e & 0x80000000u) ? (e & 0x7fffffffu) : ~e;
  return __uint_as_float(u);
}
// f32 -> bf16 (RNE) and back
__device__ __forceinline__ unsigned short f2bf(float f) {
  unsigned u = __float_as_uint(f);
  return (unsigned short)((u + 0x7FFFu + ((u >> 16) & 1u)) >> 16);
}
__device__ __forceinline__ float bf2f(unsigned short h) {
  return __uint_as_float(((unsigned)h) << 16);
}

__device__ __forceinline__ f32x4 mfma16(s16x8 a, s16x8 b, f32x4 c) {
  return __builtin_amdgcn_mfma_f32_16x16x32_bf16(a, b, c, 0, 0, 0);
}

__global__ __launch_bounds__(256) void pooled_init(unsigned* __restrict__ p) {
  p[blockIdx.x * 256 + threadIdx.x] = 0u;
}

// ---------------- build xx = [tq, x, pos] ----------------
__global__ __launch_bounds__(256) void build_xx(const float* __restrict__ x,
                                                const float* __restrict__ pos,
                                                const float* __restrict__ tq,
                                                float* __restrict__ xx, int rowoff) {
  int n = blockIdx.x * 256 + threadIdx.x;
  int g = rowoff + n;
  xx[n * 5 + 0] = tq[g];
  xx[n * 5 + 1] = x[g];
  xx[n * 5 + 2] = pos[g * 3 + 0];
  xx[n * 5 + 3] = pos[g * 3 + 1];
  xx[n * 5 + 4] = pos[g * 3 + 2];
}

// ---------------- weight prep: W[K][512] f32 -> WH/WL [512][K] bf16 ----------------
template <int K>
__global__ __launch_bounds__(256) void wprep(const float* __restrict__ W,
                                             short* __restrict__ WH,
                                             short* __restrict__ WL) {
  int idx = blockIdx.x * 256 + threadIdx.x;
  int k = idx >> 9, n = idx & 511;
  float v = W[idx];
  unsigned short h = f2bf(v);
  unsigned short lo = f2bf(v - bf2f(h));
  WH[(size_t)n * K + k] = (short)h;
  WL[(size_t)n * K + k] = (short)lo;
}

// ---------------- U = h @ (Wt - Wb), V = h @ Wb ----------------
template <int F>
__global__ __launch_bounds__(256) void uv_kernel(const float* __restrict__ h,
                                                 const float* __restrict__ W,  // [2F][64]
                                                 float* __restrict__ U,
                                                 float* __restrict__ V) {
  __shared__ float Ws[2 * F * 64];
  __shared__ float hs[16 * F];
  const int t = threadIdx.x;
  const int n0 = blockIdx.x * 16;
  for (int l = t; l < 2 * F * 64; l += 256) Ws[l] = W[l];
  for (int l = t; l < 16 * F; l += 256) hs[l] = h[(size_t)n0 * F + l];
  __syncthreads();
  for (int l = t; l < F * 64; l += 256) Ws[l] = Ws[l] - Ws[F * 64 + l];
  __syncthreads();
  const int o = t & 63;
  #pragma unroll
  for (int g4 = 0; g4 < 16; g4 += 4) {
    const int g = g4 + (t >> 6);
    float u = 0.f, v = 0.f;
    for (int f = 0; f < F; ++f) {
      float hv = hs[g * F + f];
      u += hv * Ws[f * 64 + o];
      v += hv * Ws[F * 64 + f * 64 + o];
    }
    U[(size_t)(n0 + g) * 64 + o] = u;
    V[(size_t)(n0 + g) * 64 + o] = v;
  }
}

// ---------------- sq[n] = sum_f h[n][f]^2 ----------------
template <int F>
__global__ __launch_bounds__(256) void sq_kernel(const float* __restrict__ h,
                                                 float* __restrict__ sqn) {
  int n = blockIdx.x * 4 + (threadIdx.x >> 6);
  int f = threadIdx.x & 63;
  float v = 0.f;
  if (f < F) v = h[(size_t)n * F + f];
  v *= v;
  #pragma unroll
  for (int off = 32; off > 0; off >>= 1) v += __shfl_down(v, off, 64);
  if (f == 0) sqn[n] = v;
}

#define FMA16(av, bv)                                                        \
  do {                                                                       \
    acc[0][0] += av.x * bv.x; acc[0][1] += av.x * bv.y;                      \
    acc[0][2] += av.x * bv.z; acc[0][3] += av.x * bv.w;                      \
    acc[1][0] += av.y * bv.x; acc[1][1] += av.y * bv.y;                      \
    acc[1][2] += av.y * bv.z; acc[1][3] += av.y * bv.w;                      \
    acc[2][0] += av.z * bv.x; acc[2][1] += av.z * bv.y;                      \
    acc[2][2] += av.z * bv.z; acc[2][3] += av.z * bv.w;                      \
    acc[3][0] += av.w * bv.x; acc[3][1] += av.w * bv.y;                      \
    acc[3][2] += av.w * bv.z; acc[3][3] += av.w * bv.w;                      \
  } while (0)

// ---------------- kNN v7: pipelined GEMM distances + exact (d,j) top-10 ----------------
template <int F>
__global__ __launch_bounds__(256) void knn_kernel(const float* __restrict__ h,
                                                  const float* __restrict__ sqn,
                                                  int* __restrict__ idxout) {
  constexpr int IPB = 64;
  constexpr int TJ = 64;
  constexpr int LDA = 68;   // floats; As/Bs pitch (16B-aligned rows)
  constexpr int LDD = 65;   // floats; D-tile pitch (conflict-free column reads)
  constexpr int LDM = 41;   // merge pitch
  constexpr int UNI = (IPB * LDM * 2 > TJ * LDA) ? IPB * LDM * 2 : TJ * LDA;
  __shared__ float As[F][LDA];
  __shared__ float uni[UNI];
  __shared__ float sqt[TJ];
  float* Bs = uni;                     // [F][LDA]
  float* D  = uni;                     // [IPB][LDD]
  float* md = uni;                     // merge dists [IPB][LDM]
  int*   mi = (int*)(uni + IPB * LDM); // merge idxs  [IPB][LDM]

  const int b = blockIdx.y;
  const int i0 = blockIdx.x * IPB;
  const int t = threadIdx.x;
  const int tx = t & 15, ty = t >> 4;
  const int gbase = b * Nn;
  const int r = t & 63;   // selection row
  const int s = t >> 6;   // selection j-subset (= wave id)

  // ---- stage As = h[i0..i0+63][:] transposed (conflict-light remap) ----
  if constexpr (F == 64) {
    #pragma unroll
    for (int p = 0; p < 4; ++p) {
      int row = (t & 15) + (p << 4), f4 = t >> 4;
      float4 v = *(const float4*)&h[(size_t)(gbase + i0 + row) * 64 + f4 * 4];
      As[f4 * 4 + 0][row] = v.x; As[f4 * 4 + 1][row] = v.y;
      As[f4 * 4 + 2][row] = v.z; As[f4 * 4 + 3][row] = v.w;
    }
  } else {
    for (int l = t; l < IPB * F; l += 256) {
      int row = l / F, f = l % F;
      As[f][row] = h[(size_t)(gbase + i0 + row) * F + f];
    }
  }

  // exact top-10 state (round-4/6 proven semantics)
  float bd[Kk];
  int bi[Kk];
  #pragma unroll
  for (int q = 0; q < Kk; ++q) { bd[q] = INFINITY; bi[q] = 0x7fffffff; }
  float cm = INFINITY;
  int cmi = 0x7fffffff;
  int mp = 0;

  auto insert = [&](float d, int j) {
    if (d < cm) {
      #pragma unroll
      for (int q = 0; q < Kk; ++q) {
        if (q == mp) { bd[q] = d; bi[q] = j; }
      }
      cm = -INFINITY; cmi = -1; mp = 0;
      #pragma unroll
      for (int q = 0; q < Kk; ++q) {
        bool g = (bd[q] > cm) || (bd[q] == cm && bi[q] > cmi);
        if (g) { cm = bd[q]; cmi = bi[q]; mp = q; }
      }
    }
  };

  // ---- T14-style tile prefetch registers (F==64 path) ----
  float4 stv[4];
  if constexpr (F == 64) {
    #pragma unroll
    for (int p = 0; p < 4; ++p) {
      int row = (t & 15) + (p << 4);
      stv[p] = *(const float4*)&h[(size_t)(gbase + row) * 64 + (t >> 4) * 4];
    }
  }

  for (int jt = 0; jt < Nn; jt += TJ) {
    __syncthreads();  // previous selection done reading D (aliases Bs)
    // ---- stage Bs transposed + sqt; issue next tile's loads ----
    if constexpr (F == 64) {
      #pragma unroll
      for (int p = 0; p < 4; ++p) {
        int row = (t & 15) + (p << 4), f4 = t >> 4;
        Bs[(f4 * 4 + 0) * LDA + row] = stv[p].x;
        Bs[(f4 * 4 + 1) * LDA + row] = stv[p].y;
        Bs[(f4 * 4 + 2) * LDA + row] = stv[p].z;
        Bs[(f4 * 4 + 3) * LDA + row] = stv[p].w;
      }
    } else {
      for (int l = t; l < TJ * F; l += 256) {
        int row = l / F, f = l % F;
        Bs[f * LDA + row] = h[(size_t)(gbase + jt + row) * F + f];
      }
    }
    if (t < TJ) sqt[t] = sqn[gbase + jt + t];
    if constexpr (F == 64) {
      if (jt + TJ < Nn) {
        #pragma unroll
        for (int p = 0; p < 4; ++p) {
          int row = (t & 15) + (p << 4);
          stv[p] = *(const float4*)&h[(size_t)(gbase + jt + TJ + row) * 64 + (t >> 4) * 4];
        }
      }
    }
    __syncthreads();

    // ---- register-pipelined GEMM: acc[4i][4j] (exact f-order fmac chains) ----
    float acc[4][4] = {{0.f, 0.f, 0.f, 0.f}, {0.f, 0.f, 0.f, 0.f},
                       {0.f, 0.f, 0.f, 0.f}, {0.f, 0.f, 0.f, 0.f}};
    {
      float4 a_c = *(const float4*)&As[0][ty * 4];
      float4 b_c = *(const float4*)(Bs + tx * 4);
      #pragma unroll 4
      for (int f = 0; f < F - 1; ++f) {
        float4 a_n = *(const float4*)&As[f + 1][ty * 4];
        float4 b_n = *(const float4*)(Bs + (f + 1) * LDA + tx * 4);
        FMA16(a_c, b_c);
        a_c = a_n; b_c = b_n;
      }
      FMA16(a_c, b_c);
    }
    __syncthreads();  // Bs consumed; D may overwrite

    // ---- store exact fp32 distances to D ----
    float4 sj = *(const float4*)&sqt[tx * 4];
    #pragma unroll
    for (int ii = 0; ii < 4; ++ii) {
      float* dr = D + (ty * 4 + ii) * LDD + tx * 4;
      dr[0] = sj.x - 2.f * acc[ii][0];
      dr[1] = sj.y - 2.f * acc[ii][1];
      dr[2] = sj.z - 2.f * acc[ii][2];
      dr[3] = sj.w - 2.f * acc[ii][3];
    }
    __syncthreads();

    // ---- selection: hoisted conflict-free reads, then inserts (ascending j) ----
    {
      const float* drow = D + r * LDD + s * 16;
      float dv[16];
      #pragma unroll
      for (int qq = 0; qq < 16; ++qq) dv[qq] = drow[qq];
      #pragma unroll
      for (int qq = 0; qq < 16; ++qq) insert(dv[qq], jt + s * 16 + qq);
    }
  }

  // ---- merge 4 partial top-10s per row -> top-10 (lexicographic) ----
  __syncthreads();
  #pragma unroll
  for (int q = 0; q < Kk; ++q) {
    md[r * LDM + s * 10 + q] = bd[q];
    mi[r * LDM + s * 10 + q] = bi[q];
  }
  __syncthreads();
  if (s == 0) {
    float* rd = md + r * LDM;
    int*   ri = mi + r * LDM;
    #pragma unroll 1
    for (int q = 0; q < Kk; ++q) {
      float best = INFINITY;
      int besti = 0x7fffffff, bslot = 0;
      #pragma unroll 1
      for (int e = 0; e < 40; ++e) {
        float d = rd[e];
        int ix = ri[e];
        bool g = (d < best) || (d == best && ix < besti);
        if (g) { best = d; besti = ix; bslot = e; }
      }
      rd[bslot] = INFINITY;
      idxout[(size_t)(gbase + i0 + r) * Kk + q] = besti;
    }
  }
}

// ---------------- h_out[i] = sum_k lrelu(U[i] + V[j_k] + b); also bf16 hi/lo ----------------
__global__ __launch_bounds__(256) void agg_kernel(const float* __restrict__ U,
                                                  const float* __restrict__ V,
                                                  const int* __restrict__ idx,
                                                  const float* __restrict__ bias,
                                                  float* __restrict__ hout,
                                                  short* __restrict__ hH,
                                                  short* __restrict__ hL) {
  int t = blockIdx.x * 256 + threadIdx.x;
  int n = t >> 2;
  int o0 = (t & 3) * 16;
  int gb = n & ~(Nn - 1);
  float4 u[4], bb[4], acc[4];
  #pragma unroll
  for (int q = 0; q < 4; ++q) {
    u[q] = *(const float4*)&U[(size_t)n * 64 + o0 + q * 4];
    bb[q] = *(const float4*)&bias[o0 + q * 4];
    acc[q] = make_float4(0.f, 0.f, 0.f, 0.f);
  }
  #pragma unroll
  for (int k = 0; k < Kk; ++k) {
    int j = gb + idx[n * Kk + k];
    #pragma unroll
    for (int q = 0; q < 4; ++q) {
      float4 v = *(const float4*)&V[(size_t)j * 64 + o0 + q * 4];
      acc[q].x += lrelu(u[q].x + v.x + bb[q].x);
      acc[q].y += lrelu(u[q].y + v.y + bb[q].y);
      acc[q].z += lrelu(u[q].z + v.z + bb[q].z);
      acc[q].w += lrelu(u[q].w + v.w + bb[q].w);
    }
  }
  #pragma unroll
  for (int q = 0; q < 4; ++q) {
    *(float4*)&hout[(size_t)n * 64 + o0 + q * 4] = acc[q];
    ushort4 hv, lv;
    hv.x = f2bf(acc[q].x); lv.x = f2bf(acc[q].x - bf2f(hv.x));
    hv.y = f2bf(acc[q].y); lv.y = f2bf(acc[q].y - bf2f(hv.y));
    hv.z = f2bf(acc[q].z); lv.z = f2bf(acc[q].z - bf2f(hv.z));
    hv.w = f2bf(acc[q].w); lv.w = f2bf(acc[q].w - bf2f(hv.w));
    *(ushort4*)&hH[(size_t)n * 64 + o0 + q * 4] = hv;
    *(ushort4*)&hL[(size_t)n * 64 + o0 + q * 4] = lv;
  }
}

// ---------------- MFMA bf16x2 (hi/lo, 3-term) GEMM, 128x128 tile ----------------
// MODE 0: A = h (6 slots [Msl][64] bf16 pair), K=384 -> z = lrelu(A@B + bias) (bf16 pair, local rows)
// MODE 1: A = z ([Mz][512] bf16 pair), K=512 -> fused maxpool atomicMax(pooled)
// B operands pre-transposed [512][Kdim].
template <int MODE>
__global__ __launch_bounds__(256) void mfma_gemm(const short* __restrict__ AH,
                                                 const short* __restrict__ AL,
                                                 const short* __restrict__ BH,
                                                 const short* __restrict__ BL,
                                                 const float* __restrict__ bias,
                                                 short* __restrict__ outH,
                                                 short* __restrict__ outL,
                                                 unsigned* __restrict__ pooled,
                                                 int Msl, int zc, int g0) {
  constexpr int Kdim = (MODE == 0) ? 384 : 512;
  __shared__ short AHs[128][40], ALs[128][40], BHs[128][40], BLs[128][40];
  __shared__ float red[8][132];
  const int t = threadIdx.x;
  const int m0 = blockIdx.y * 128, n0 = blockIdx.x * 128;
  const int w = t >> 6, l = t & 63;
  const int q = w >> 1, p = w & 1, rl = l & 15, kb = l >> 4;
  const int srow = t >> 1, sc = (t & 1) * 16;

  f32x4 acc[4][4];
  #pragma unroll
  for (int m = 0; m < 4; ++m)
    #pragma unroll
    for (int n = 0; n < 4; ++n) acc[m][n] = (f32x4){0.f, 0.f, 0.f, 0.f};

  for (int k0 = 0; k0 < Kdim; k0 += 32) {
    size_t aoff, boff;
    if constexpr (MODE == 0)
      aoff = ((size_t)(k0 >> 6) * Msl + zc + m0 + srow) * 64 + (k0 & 63) + sc;
    else
      aoff = (size_t)(m0 + srow) * 512 + k0 + sc;
    boff = (size_t)(n0 + srow) * Kdim + k0 + sc;
    __syncthreads();
    *(uint4*)&AHs[srow][sc]     = *(const uint4*)(AH + aoff);
    *(uint4*)&AHs[srow][sc + 8] = *(const uint4*)(AH + aoff + 8);
    *(uint4*)&ALs[srow][sc]     = *(const uint4*)(AL + aoff);
    *(uint4*)&ALs[srow][sc + 8] = *(const uint4*)(AL + aoff + 8);
    *(uint4*)&BHs[srow][sc]     = *(const uint4*)(BH + boff);
    *(uint4*)&BHs[srow][sc + 8] = *(const uint4*)(BH + boff + 8);
    *(uint4*)&BLs[srow][sc]     = *(const uint4*)(BL + boff);
    *(uint4*)&BLs[srow][sc + 8] = *(const uint4*)(BL + boff + 8);
    __syncthreads();

    s16x8 aH[4], aL[4], bH[4], bL[4];
    #pragma unroll
    for (int m = 0; m < 4; ++m) {
      aH[m] = *(const s16x8*)&AHs[q * 64 + m * 16 + rl][kb * 8];
      aL[m] = *(const s16x8*)&ALs[q * 64 + m * 16 + rl][kb * 8];
    }
    #pragma unroll
    for (int n = 0; n < 4; ++n) {
      bH[n] = *(const s16x8*)&BHs[p * 64 + n * 16 + rl][kb * 8];
      bL[n] = *(const s16x8*)&BLs[p * 64 + n * 16 + rl][kb * 8];
    }
    #pragma unroll
    for (int m = 0; m < 4; ++m)
      #pragma unroll
      for (int n = 0; n < 4; ++n) {
        acc[m][n] = mfma16(aH[m], bH[n], acc[m][n]);
        acc[m][n] = mfma16(aH[m], bL[n], acc[m][n]);
        acc[m][n] = mfma16(aL[m], bH[n], acc[m][n]);
      }
  }

  if constexpr (MODE == 0) {
    #pragma unroll
    for (int n = 0; n < 4; ++n) {
      const int col = n0 + p * 64 + n * 16 + rl;
      const float bv = bias[col];
      #pragma unroll
      for (int m = 0; m < 4; ++m) {
        #pragma unroll
        for (int rr = 0; rr < 4; ++rr) {
          int row = m0 + q * 64 + m * 16 + kb * 4 + rr;
          float v = lrelu(acc[m][n][rr] + bv);
          unsigned short hv = f2bf(v);
          unsigned short lv = f2bf(v - bf2f(hv));
          outH[(size_t)row * 512 + col] = (short)hv;
          outL[(size_t)row * 512 + col] = (short)lv;
        }
      }
    }
  } else {
    #pragma unroll
    for (int n = 0; n < 4; ++n) {
      float cm = acc[0][n][0];
      #pragma unroll
      for (int m = 0; m < 4; ++m)
        #pragma unroll
        for (int rr = 0; rr < 4; ++rr) cm = fmaxf(cm, acc[m][n][rr]);
      red[q * 4 + kb][p * 64 + n * 16 + rl] = cm;
    }
    __syncthreads();
    if (t < 128) {
      float m = red[0][t];
      #pragma unroll
      for (int rr = 1; rr < 8; ++rr) m = fmaxf(m, red[rr][t]);
      m += bias[n0 + t];
      int g = g0 + ((zc + m0) >> 10);
      atomicMax(&pooled[(size_t)g * 512 + n0 + t], encf(m));
    }
  }
}

// ---------------- head: per graph, lrelu(pooled@Wm1+bm1)@Wm2+bm2 ----------------
__global__ __launch_bounds__(256) void head_kernel(const unsigned* __restrict__ pooled,
                                                   const float* __restrict__ Wm1,
                                                   const float* __restrict__ bm1,
                                                   const float* __restrict__ Wm2,
                                                   const float* __restrict__ bm2,
                                                   float* __restrict__ out) {
  __shared__ float ps[512];
  __shared__ float hs[256];
  int b = blockIdx.x;
  int t = threadIdx.x;
  for (int l = t; l < 512; l += 256) ps[l] = decf(pooled[(size_t)b * 512 + l]);
  __syncthreads();
  float acc = bm1[t];
  for (int f = 0; f < 512; ++f) acc += ps[f] * Wm1[f * 256 + t];
  hs[t] = lrelu(acc);
  __syncthreads();
  if (t < 3) {
    float y = bm2[t];
    for (int f = 0; f < 256; ++f) y += hs[f] * Wm2[f * 3 + t];
    out[b * 3 + t] = y;
  }
}

static inline size_t al256(size_t v) { return (v + 255) & ~(size_t)255; }

extern "C" void kernel_launch(void* const* d_in, const int* in_sizes, int n_in,
                              void* d_out, int out_size, void* d_ws, size_t ws_size,
                              hipStream_t stream) {
  (void)in_sizes; (void)n_in; (void)out_size;
  const float* x    = (const float*)d_in[0];
  const float* pos  = (const float*)d_in[1];
  const float* tq   = (const float*)d_in[2];
  // d_in[3] = batch (uniform & sorted; unused)
  const float* W1   = (const float*)d_in[4];
  const float* b1   = (const float*)d_in[5];
  const float* W2   = (const float*)d_in[6];
  const float* b2   = (const float*)d_in[7];
  const float* Wl1a = (const float*)d_in[8];
  const float* bl1a = (const float*)d_in[9];
  const float* Wl1b = (const float*)d_in[10];
  const float* bl1b = (const float*)d_in[11];
  const float* Wm1  = (const float*)d_in[12];
  const float* bm1  = (const float*)d_in[13];
  const float* Wm2  = (const float*)d_in[14];
  const float* bm2  = (const float*)d_in[15];
  float* out = (float*)d_out;

  // ---- pick largest graph-chunk G whose workspace fits ----
  auto calc = [&](int G, size_t& hcB, size_t& hHB, size_t& uniB, size_t& wB) -> size_t {
    size_t M = (size_t)G * Nn;
    hcB = al256(M * 384 * 4);        // f32 hc (6 slots [M][64])
    hHB = al256(M * 384 * 2);        // bf16 hi (and lo) copies
    size_t convS = al256(M * 5 * 4) + 2 * al256(M * 64 * 4) +
                   al256(M * 4) + al256(M * Kk * 4);
    size_t Mz = M < 16384 ? M : 16384;
    size_t zB = 2 * al256(Mz * 512 * 2);  // zH + zL bf16
    uniB = convS > zB ? convS : zB;
    wB = 2 * al256((size_t)512 * 384 * 2) + 2 * al256((size_t)512 * 512 * 2);
    return hcB + 2 * hHB + uniB + al256((size_t)Bg * 512 * 4) + wB + 1024;
  };
  int G = 64;
  size_t hcB = 0, hHB = 0, uniB = 0, wB = 0;
  while (G > 1 && calc(G, hcB, hHB, uniB, wB) > ws_size) G >>= 1;
  calc(G, hcB, hHB, uniB, wB);
  const int M = G * Nn;
  const int Mz = M < 16384 ? M : 16384;

  char* w = (char*)d_ws;
  float*    hc  = (float*)w;
  short*    hH  = (short*)(w + hcB);
  short*    hL  = (short*)(w + hcB + hHB);
  char*     uni = w + hcB + 2 * hHB;
  float*    xx  = (float*)uni;
  float*    U   = (float*)(uni + al256((size_t)M * 5 * 4));
  float*    V   = (float*)((char*)U + al256((size_t)M * 64 * 4));
  float*    sqn = (float*)((char*)V + al256((size_t)M * 64 * 4));
  int*      idx = (int*)((char*)sqn + al256((size_t)M * 4));
  short*    zH  = (short*)uni;                               // MLP phase aliases conv scratch
  short*    zL  = (short*)(uni + al256((size_t)Mz * 512 * 2));
  unsigned* pooled = (unsigned*)(uni + uniB);
  short*    WHa = (short*)((char*)pooled + al256((size_t)Bg * 512 * 4));
  short*    WLa = WHa + (size_t)512 * 384;
  short*    WHb = (short*)((char*)WHa + 2 * al256((size_t)512 * 384 * 2));
  short*    WLb = WHb + (size_t)512 * 512;

  wprep<384><<<(384 * 512) / 256, 256, 0, stream>>>(Wl1a, WHa, WLa);
  wprep<512><<<(512 * 512) / 256, 256, 0, stream>>>(Wl1b, WHb, WLb);
  pooled_init<<<(Bg * 512) / 256, 256, 0, stream>>>(pooled);

  for (int g0 = 0; g0 < Bg; g0 += G) {
    build_xx<<<M / 256, 256, 0, stream>>>(x, pos, tq, xx, g0 * Nn);

    // conv1 (F=5, W1) -> slot 0
    uv_kernel<5><<<M / 16, 256, 0, stream>>>(xx, W1, U, V);
    sq_kernel<5><<<M / 4, 256, 0, stream>>>(xx, sqn);
    knn_kernel<5><<<dim3(Nn / 64, G), 256, 0, stream>>>(xx, sqn, idx);
    agg_kernel<<<M / 64, 256, 0, stream>>>(U, V, idx, b1, hc, hH, hL);

    // conv2..6 (F=64, shared W2) -> slots 1..5
    for (int c = 1; c < 6; ++c) {
      const float* hin = hc + (size_t)(c - 1) * M * 64;
      uv_kernel<64><<<M / 16, 256, 0, stream>>>(hin, W2, U, V);
      sq_kernel<64><<<M / 4, 256, 0, stream>>>(hin, sqn);
      knn_kernel<64><<<dim3(Nn / 64, G), 256, 0, stream>>>(hin, sqn, idx);
      agg_kernel<<<M / 64, 256, 0, stream>>>(U, V, idx, b2,
                                             hc + (size_t)c * M * 64,
                                             hH + (size_t)c * M * 64,
                                             hL + (size_t)c * M * 64);
    }

    // MLP over this chunk's rows, z-chunked
    for (int zc = 0; zc < M; zc += Mz) {
      mfma_gemm<0><<<dim3(4, Mz / 128), 256, 0, stream>>>(hH, hL, WHa, WLa, bl1a,
                                                          zH, zL, nullptr, M, zc, 0);
      mfma_gemm<1><<<dim3(4, Mz / 128), 256, 0, stream>>>(zH, zL, WHb, WLb, bl1b,
                                                          nullptr, nullptr, pooled, Mz, zc, g0);
    }
  }

  head_kernel<<<Bg, 256, 0, stream>>>(pooled, Wm1, bm1, Wm2, bm2, out);
}

// Round 8
// 2427.215 us; speedup vs baseline: 3.1453x; 1.2349x over previous
//
#include <hip/hip_runtime.h>
#include <cstdint>
#include <cstddef>

constexpr int Bg = 64;     // graphs
constexpr int Nn = 1024;   // nodes per graph
constexpr int Kk = 10;     // kNN neighbors
constexpr int BN = Bg * Nn;
#define SLOPE 0.01f

typedef __attribute__((ext_vector_type(8))) short s16x8;
typedef __attribute__((ext_vector_type(4))) float f32x4;

__device__ __forceinline__ float lrelu(float v) { return v >= 0.f ? v : SLOPE * v; }

// order-preserving float -> uint encoding
__device__ __forceinline__ unsigned encf(float f) {
  unsigned u = __float_as_uint(f);
  return (u & 0x80000000u) ? ~u : (u | 0x80000000u);
}
__device__ __forceinline__ float decf(unsigned e) {
  unsigned u = (e & 0x80000000u) ? (e & 0x7fffffffu) : ~e;
  return __uint_as_float(u);
}
// f32 -> bf16 (RNE) and back
__device__ __forceinline__ unsigned short f2bf(float f) {
  unsigned u = __float_as_uint(f);
  return (unsigned short)((u + 0x7FFFu + ((u >> 16) & 1u)) >> 16);
}
__device__ __forceinline__ float bf2f(unsigned short h) {
  return __uint_as_float(((unsigned)h) << 16);
}

__device__ __forceinline__ f32x4 mfma16(s16x8 a, s16x8 b, f32x4 c) {
  return __builtin_amdgcn_mfma_f32_16x16x32_bf16(a, b, c, 0, 0, 0);
}

__global__ __launch_bounds__(256) void pooled_init(unsigned* __restrict__ p) {
  p[blockIdx.x * 256 + threadIdx.x] = 0u;
}

// ---------------- build xx = [tq, x, pos] ----------------
__global__ __launch_bounds__(256) void build_xx(const float* __restrict__ x,
                                                const float* __restrict__ pos,
                                                const float* __restrict__ tq,
                                                float* __restrict__ xx, int rowoff) {
  int n = blockIdx.x * 256 + threadIdx.x;
  int g = rowoff + n;
  xx[n * 5 + 0] = tq[g];
  xx[n * 5 + 1] = x[g];
  xx[n * 5 + 2] = pos[g * 3 + 0];
  xx[n * 5 + 3] = pos[g * 3 + 1];
  xx[n * 5 + 4] = pos[g * 3 + 2];
}

// ---------------- weight prep: W[K][512] f32 -> WH/WL [512][K] bf16 ----------------
template <int K>
__global__ __launch_bounds__(256) void wprep(const float* __restrict__ W,
                                             short* __restrict__ WH,
                                             short* __restrict__ WL) {
  int idx = blockIdx.x * 256 + threadIdx.x;
  int k = idx >> 9, n = idx & 511;
  float v = W[idx];
  unsigned short h = f2bf(v);
  unsigned short lo = f2bf(v - bf2f(h));
  WH[(size_t)n * K + k] = (short)h;
  WL[(size_t)n * K + k] = (short)lo;
}

// ---------------- U = h @ (Wt - Wb), V = h @ Wb ----------------
template <int F>
__global__ __launch_bounds__(256) void uv_kernel(const float* __restrict__ h,
                                                 const float* __restrict__ W,  // [2F][64]
                                                 float* __restrict__ U,
                                                 float* __restrict__ V) {
  __shared__ float Ws[2 * F * 64];
  __shared__ float hs[16 * F];
  const int t = threadIdx.x;
  const int n0 = blockIdx.x * 16;
  for (int l = t; l < 2 * F * 64; l += 256) Ws[l] = W[l];
  for (int l = t; l < 16 * F; l += 256) hs[l] = h[(size_t)n0 * F + l];
  __syncthreads();
  for (int l = t; l < F * 64; l += 256) Ws[l] = Ws[l] - Ws[F * 64 + l];
  __syncthreads();
  const int o = t & 63;
  #pragma unroll
  for (int g4 = 0; g4 < 16; g4 += 4) {
    const int g = g4 + (t >> 6);
    float u = 0.f, v = 0.f;
    for (int f = 0; f < F; ++f) {
      float hv = hs[g * F + f];
      u += hv * Ws[f * 64 + o];
      v += hv * Ws[F * 64 + f * 64 + o];
    }
    U[(size_t)(n0 + g) * 64 + o] = u;
    V[(size_t)(n0 + g) * 64 + o] = v;
  }
}

// ---------------- sq[n] = sum_f h[n][f]^2 ----------------
template <int F>
__global__ __launch_bounds__(256) void sq_kernel(const float* __restrict__ h,
                                                 float* __restrict__ sqn) {
  int n = blockIdx.x * 4 + (threadIdx.x >> 6);
  int f = threadIdx.x & 63;
  float v = 0.f;
  if (f < F) v = h[(size_t)n * F + f];
  v *= v;
  #pragma unroll
  for (int off = 32; off > 0; off >>= 1) v += __shfl_down(v, off, 64);
  if (f == 0) sqn[n] = v;
}

#define FMA16(av, bv)                                                        \
  do {                                                                       \
    acc[0][0] += av.x * bv.x; acc[0][1] += av.x * bv.y;                      \
    acc[0][2] += av.x * bv.z; acc[0][3] += av.x * bv.w;                      \
    acc[1][0] += av.y * bv.x; acc[1][1] += av.y * bv.y;                      \
    acc[1][2] += av.y * bv.z; acc[1][3] += av.y * bv.w;                      \
    acc[2][0] += av.z * bv.x; acc[2][1] += av.z * bv.y;                      \
    acc[2][2] += av.z * bv.z; acc[2][3] += av.z * bv.w;                      \
    acc[3][0] += av.w * bv.x; acc[3][1] += av.w * bv.y;                      \
    acc[3][2] += av.w * bv.z; acc[3][3] += av.w * bv.w;                      \
  } while (0)

// ---------------- kNN v8: pipelined GEMM distances + branchless exact (d,j) ladder ----------------
template <int F>
__global__ __launch_bounds__(256) void knn_kernel(const float* __restrict__ h,
                                                  const float* __restrict__ sqn,
                                                  int* __restrict__ idxout) {
  constexpr int IPB = 64;
  constexpr int TJ = 64;
  constexpr int LDA = 68;   // floats; As/Bs pitch (16B-aligned rows)
  constexpr int LDD = 65;   // floats; D-tile pitch (conflict-free column reads)
  constexpr int LDM = 41;   // merge pitch
  constexpr int UNI = (IPB * LDM * 2 > TJ * LDA) ? IPB * LDM * 2 : TJ * LDA;
  __shared__ float As[F][LDA];
  __shared__ float uni[UNI];
  __shared__ float sqt[TJ];
  float* Bs = uni;                     // [F][LDA]
  float* D  = uni;                     // [IPB][LDD]
  float* md = uni;                     // merge dists [IPB][LDM]
  int*   mi = (int*)(uni + IPB * LDM); // merge idxs  [IPB][LDM]

  const int b = blockIdx.y;
  const int i0 = blockIdx.x * IPB;
  const int t = threadIdx.x;
  const int tx = t & 15, ty = t >> 4;
  const int gbase = b * Nn;
  const int r = t & 63;   // selection row
  const int s = t >> 6;   // selection j-subset (= wave id)

  // ---- stage As = h[i0..i0+63][:] transposed (conflict-light remap) ----
  if constexpr (F == 64) {
    #pragma unroll
    for (int p = 0; p < 4; ++p) {
      int row = (t & 15) + (p << 4), f4 = t >> 4;
      float4 v = *(const float4*)&h[(size_t)(gbase + i0 + row) * 64 + f4 * 4];
      As[f4 * 4 + 0][row] = v.x; As[f4 * 4 + 1][row] = v.y;
      As[f4 * 4 + 2][row] = v.z; As[f4 * 4 + 3][row] = v.w;
    }
  } else {
    for (int l = t; l < IPB * F; l += 256) {
      int row = l / F, f = l % F;
      As[f][row] = h[(size_t)(gbase + i0 + row) * F + f];
    }
  }

  // ---- branchless sorted top-10 state: (bd,bj) pairs ascending by d ----
  // Stable strict-< ladder + ascending-j insertion order == exact (d,j) lexicographic.
  float bd0 = INFINITY, bd1 = INFINITY, bd2 = INFINITY, bd3 = INFINITY, bd4 = INFINITY,
        bd5 = INFINITY, bd6 = INFINITY, bd7 = INFINITY, bd8 = INFINITY, bd9 = INFINITY;
  int bj0 = 0x7fffffff, bj1 = 0x7fffffff, bj2 = 0x7fffffff, bj3 = 0x7fffffff, bj4 = 0x7fffffff,
      bj5 = 0x7fffffff, bj6 = 0x7fffffff, bj7 = 0x7fffffff, bj8 = 0x7fffffff, bj9 = 0x7fffffff;

  auto ins = [&](float kd, int kj) {
    // top-down: new_bq = maxp(b_{q-1}^old, minp(b_q^old, k)); b0 = minp(b0,k)
    bool m9 = kd < bd9; float t9d = m9 ? kd : bd9; int t9j = m9 ? kj : bj9;
    bool x9 = t9d < bd8; bd9 = x9 ? bd8 : t9d; bj9 = x9 ? bj8 : t9j;
    bool m8 = kd < bd8; float t8d = m8 ? kd : bd8; int t8j = m8 ? kj : bj8;
    bool x8 = t8d < bd7; bd8 = x8 ? bd7 : t8d; bj8 = x8 ? bj7 : t8j;
    bool m7 = kd < bd7; float t7d = m7 ? kd : bd7; int t7j = m7 ? kj : bj7;
    bool x7 = t7d < bd6; bd7 = x7 ? bd6 : t7d; bj7 = x7 ? bj6 : t7j;
    bool m6 = kd < bd6; float t6d = m6 ? kd : bd6; int t6j = m6 ? kj : bj6;
    bool x6 = t6d < bd5; bd6 = x6 ? bd5 : t6d; bj6 = x6 ? bj5 : t6j;
    bool m5 = kd < bd5; float t5d = m5 ? kd : bd5; int t5j = m5 ? kj : bj5;
    bool x5 = t5d < bd4; bd5 = x5 ? bd4 : t5d; bj5 = x5 ? bj4 : t5j;
    bool m4 = kd < bd4; float t4d = m4 ? kd : bd4; int t4j = m4 ? kj : bj4;
    bool x4 = t4d < bd3; bd4 = x4 ? bd3 : t4d; bj4 = x4 ? bj3 : t4j;
    bool m3 = kd < bd3; float t3d = m3 ? kd : bd3; int t3j = m3 ? kj : bj3;
    bool x3 = t3d < bd2; bd3 = x3 ? bd2 : t3d; bj3 = x3 ? bj2 : t3j;
    bool m2 = kd < bd2; float t2d = m2 ? kd : bd2; int t2j = m2 ? kj : bj2;
    bool x2 = t2d < bd1; bd2 = x2 ? bd1 : t2d; bj2 = x2 ? bj1 : t2j;
    bool m1 = kd < bd1; float t1d = m1 ? kd : bd1; int t1j = m1 ? kj : bj1;
    bool x1 = t1d < bd0; bd1 = x1 ? bd0 : t1d; bj1 = x1 ? bj0 : t1j;
    bool m0 = kd < bd0; bd0 = m0 ? kd : bd0; bj0 = m0 ? kj : bj0;
  };

  // ---- T14-style tile prefetch registers (F==64 path) ----
  float4 stv[4];
  if constexpr (F == 64) {
    #pragma unroll
    for (int p = 0; p < 4; ++p) {
      int row = (t & 15) + (p << 4);
      stv[p] = *(const float4*)&h[(size_t)(gbase + row) * 64 + (t >> 4) * 4];
    }
  }

  for (int jt = 0; jt < Nn; jt += TJ) {
    __syncthreads();  // previous selection done reading D (aliases Bs)
    // ---- stage Bs transposed + sqt; issue next tile's loads ----
    if constexpr (F == 64) {
      #pragma unroll
      for (int p = 0; p < 4; ++p) {
        int row = (t & 15) + (p << 4), f4 = t >> 4;
        Bs[(f4 * 4 + 0) * LDA + row] = stv[p].x;
        Bs[(f4 * 4 + 1) * LDA + row] = stv[p].y;
        Bs[(f4 * 4 + 2) * LDA + row] = stv[p].z;
        Bs[(f4 * 4 + 3) * LDA + row] = stv[p].w;
      }
    } else {
      for (int l = t; l < TJ * F; l += 256) {
        int row = l / F, f = l % F;
        Bs[f * LDA + row] = h[(size_t)(gbase + jt + row) * F + f];
      }
    }
    if (t < TJ) sqt[t] = sqn[gbase + jt + t];
    if constexpr (F == 64) {
      if (jt + TJ < Nn) {
        #pragma unroll
        for (int p = 0; p < 4; ++p) {
          int row = (t & 15) + (p << 4);
          stv[p] = *(const float4*)&h[(size_t)(gbase + jt + TJ + row) * 64 + (t >> 4) * 4];
        }
      }
    }
    __syncthreads();

    // ---- register-pipelined GEMM: acc[4i][4j] (exact f-order fmac chains) ----
    float acc[4][4] = {{0.f, 0.f, 0.f, 0.f}, {0.f, 0.f, 0.f, 0.f},
                       {0.f, 0.f, 0.f, 0.f}, {0.f, 0.f, 0.f, 0.f}};
    {
      float4 a_c = *(const float4*)&As[0][ty * 4];
      float4 b_c = *(const float4*)(Bs + tx * 4);
      #pragma unroll 4
      for (int f = 0; f < F - 1; ++f) {
        float4 a_n = *(const float4*)&As[f + 1][ty * 4];
        float4 b_n = *(const float4*)(Bs + (f + 1) * LDA + tx * 4);
        FMA16(a_c, b_c);
        a_c = a_n; b_c = b_n;
      }
      FMA16(a_c, b_c);
    }
    __syncthreads();  // Bs consumed; D may overwrite

    // ---- store exact fp32 distances to D ----
    float4 sj = *(const float4*)&sqt[tx * 4];
    #pragma unroll
    for (int ii = 0; ii < 4; ++ii) {
      float* dr = D + (ty * 4 + ii) * LDD + tx * 4;
      dr[0] = sj.x - 2.f * acc[ii][0];
      dr[1] = sj.y - 2.f * acc[ii][1];
      dr[2] = sj.z - 2.f * acc[ii][2];
      dr[3] = sj.w - 2.f * acc[ii][3];
    }
    __syncthreads();

    // ---- selection: hoisted conflict-free reads, branchless ladder (ascending j) ----
    {
      const float* drow = D + r * LDD + s * 16;
      float dv[16];
      #pragma unroll
      for (int qq = 0; qq < 16; ++qq) dv[qq] = drow[qq];
      #pragma unroll
      for (int qq = 0; qq < 16; ++qq) ins(dv[qq], jt + s * 16 + qq);
    }
  }

  // ---- merge 4 partial sorted-10s per row -> top-10 (lexicographic) ----
  __syncthreads();
  {
    float* rd = md + r * LDM + s * 10;
    int*   ri = mi + r * LDM + s * 10;
    rd[0] = bd0; rd[1] = bd1; rd[2] = bd2; rd[3] = bd3; rd[4] = bd4;
    rd[5] = bd5; rd[6] = bd6; rd[7] = bd7; rd[8] = bd8; rd[9] = bd9;
    ri[0] = bj0; ri[1] = bj1; ri[2] = bj2; ri[3] = bj3; ri[4] = bj4;
    ri[5] = bj5; ri[6] = bj6; ri[7] = bj7; ri[8] = bj8; ri[9] = bj9;
  }
  __syncthreads();
  if (s == 0) {
    float* rd = md + r * LDM;
    int*   ri = mi + r * LDM;
    #pragma unroll 1
    for (int q = 0; q < Kk; ++q) {
      float best = INFINITY;
      int besti = 0x7fffffff, bslot = 0;
      #pragma unroll 1
      for (int e = 0; e < 40; ++e) {
        float d = rd[e];
        int ix = ri[e];
        bool g = (d < best) || (d == best && ix < besti);
        if (g) { best = d; besti = ix; bslot = e; }
      }
      rd[bslot] = INFINITY;
      idxout[(size_t)(gbase + i0 + r) * Kk + q] = besti;
    }
  }
}

// ---------------- h_out[i] = sum_k lrelu(U[i] + V[j_k] + b); also bf16 hi/lo ----------------
__global__ __launch_bounds__(256) void agg_kernel(const float* __restrict__ U,
                                                  const float* __restrict__ V,
                                                  const int* __restrict__ idx,
                                                  const float* __restrict__ bias,
                                                  float* __restrict__ hout,
                                                  short* __restrict__ hH,
                                                  short* __restrict__ hL) {
  int t = blockIdx.x * 256 + threadIdx.x;
  int n = t >> 2;
  int o0 = (t & 3) * 16;
  int gb = n & ~(Nn - 1);
  float4 u[4], bb[4], acc[4];
  #pragma unroll
  for (int q = 0; q < 4; ++q) {
    u[q] = *(const float4*)&U[(size_t)n * 64 + o0 + q * 4];
    bb[q] = *(const float4*)&bias[o0 + q * 4];
    acc[q] = make_float4(0.f, 0.f, 0.f, 0.f);
  }
  #pragma unroll
  for (int k = 0; k < Kk; ++k) {
    int j = gb + idx[n * Kk + k];
    #pragma unroll
    for (int q = 0; q < 4; ++q) {
      float4 v = *(const float4*)&V[(size_t)j * 64 + o0 + q * 4];
      acc[q].x += lrelu(u[q].x + v.x + bb[q].x);
      acc[q].y += lrelu(u[q].y + v.y + bb[q].y);
      acc[q].z += lrelu(u[q].z + v.z + bb[q].z);
      acc[q].w += lrelu(u[q].w + v.w + bb[q].w);
    }
  }
  #pragma unroll
  for (int q = 0; q < 4; ++q) {
    *(float4*)&hout[(size_t)n * 64 + o0 + q * 4] = acc[q];
    ushort4 hv, lv;
    hv.x = f2bf(acc[q].x); lv.x = f2bf(acc[q].x - bf2f(hv.x));
    hv.y = f2bf(acc[q].y); lv.y = f2bf(acc[q].y - bf2f(hv.y));
    hv.z = f2bf(acc[q].z); lv.z = f2bf(acc[q].z - bf2f(hv.z));
    hv.w = f2bf(acc[q].w); lv.w = f2bf(acc[q].w - bf2f(hv.w));
    *(ushort4*)&hH[(size_t)n * 64 + o0 + q * 4] = hv;
    *(ushort4*)&hL[(size_t)n * 64 + o0 + q * 4] = lv;
  }
}

// ---------------- MFMA bf16x2 (hi/lo, 3-term) GEMM, 128x128 tile ----------------
// MODE 0: A = h (6 slots [Msl][64] bf16 pair), K=384 -> z = lrelu(A@B + bias) (bf16 pair, local rows)
// MODE 1: A = z ([Mz][512] bf16 pair), K=512 -> fused maxpool atomicMax(pooled)
// B operands pre-transposed [512][Kdim].
template <int MODE>
__global__ __launch_bounds__(256) void mfma_gemm(const short* __restrict__ AH,
                                                 const short* __restrict__ AL,
                                                 const short* __restrict__ BH,
                                                 const short* __restrict__ BL,
                                                 const float* __restrict__ bias,
                                                 short* __restrict__ outH,
                                                 short* __restrict__ outL,
                                                 unsigned* __restrict__ pooled,
                                                 int Msl, int zc, int g0) {
  constexpr int Kdim = (MODE == 0) ? 384 : 512;
  __shared__ short AHs[128][40], ALs[128][40], BHs[128][40], BLs[128][40];
  __shared__ float red[8][132];
  const int t = threadIdx.x;
  const int m0 = blockIdx.y * 128, n0 = blockIdx.x * 128;
  const int w = t >> 6, l = t & 63;
  const int q = w >> 1, p = w & 1, rl = l & 15, kb = l >> 4;
  const int srow = t >> 1, sc = (t & 1) * 16;

  f32x4 acc[4][4];
  #pragma unroll
  for (int m = 0; m < 4; ++m)
    #pragma unroll
    for (int n = 0; n < 4; ++n) acc[m][n] = (f32x4){0.f, 0.f, 0.f, 0.f};

  for (int k0 = 0; k0 < Kdim; k0 += 32) {
    size_t aoff, boff;
    if constexpr (MODE == 0)
      aoff = ((size_t)(k0 >> 6) * Msl + zc + m0 + srow) * 64 + (k0 & 63) + sc;
    else
      aoff = (size_t)(m0 + srow) * 512 + k0 + sc;
    boff = (size_t)(n0 + srow) * Kdim + k0 + sc;
    __syncthreads();
    *(uint4*)&AHs[srow][sc]     = *(const uint4*)(AH + aoff);
    *(uint4*)&AHs[srow][sc + 8] = *(const uint4*)(AH + aoff + 8);
    *(uint4*)&ALs[srow][sc]     = *(const uint4*)(AL + aoff);
    *(uint4*)&ALs[srow][sc + 8] = *(const uint4*)(AL + aoff + 8);
    *(uint4*)&BHs[srow][sc]     = *(const uint4*)(BH + boff);
    *(uint4*)&BHs[srow][sc + 8] = *(const uint4*)(BH + boff + 8);
    *(uint4*)&BLs[srow][sc]     = *(const uint4*)(BL + boff);
    *(uint4*)&BLs[srow][sc + 8] = *(const uint4*)(BL + boff + 8);
    __syncthreads();

    s16x8 aH[4], aL[4], bH[4], bL[4];
    #pragma unroll
    for (int m = 0; m < 4; ++m) {
      aH[m] = *(const s16x8*)&AHs[q * 64 + m * 16 + rl][kb * 8];
      aL[m] = *(const s16x8*)&ALs[q * 64 + m * 16 + rl][kb * 8];
    }
    #pragma unroll
    for (int n = 0; n < 4; ++n) {
      bH[n] = *(const s16x8*)&BHs[p * 64 + n * 16 + rl][kb * 8];
      bL[n] = *(const s16x8*)&BLs[p * 64 + n * 16 + rl][kb * 8];
    }
    #pragma unroll
    for (int m = 0; m < 4; ++m)
      #pragma unroll
      for (int n = 0; n < 4; ++n) {
        acc[m][n] = mfma16(aH[m], bH[n], acc[m][n]);
        acc[m][n] = mfma16(aH[m], bL[n], acc[m][n]);
        acc[m][n] = mfma16(aL[m], bH[n], acc[m][n]);
      }
  }

  if constexpr (MODE == 0) {
    #pragma unroll
    for (int n = 0; n < 4; ++n) {
      const int col = n0 + p * 64 + n * 16 + rl;
      const float bv = bias[col];
      #pragma unroll
      for (int m = 0; m < 4; ++m) {
        #pragma unroll
        for (int rr = 0; rr < 4; ++rr) {
          int row = m0 + q * 64 + m * 16 + kb * 4 + rr;
          float v = lrelu(acc[m][n][rr] + bv);
          unsigned short hv = f2bf(v);
          unsigned short lv = f2bf(v - bf2f(hv));
          outH[(size_t)row * 512 + col] = (short)hv;
          outL[(size_t)row * 512 + col] = (short)lv;
        }
      }
    }
  } else {
    #pragma unroll
    for (int n = 0; n < 4; ++n) {
      float cm = acc[0][n][0];
      #pragma unroll
      for (int m = 0; m < 4; ++m)
        #pragma unroll
        for (int rr = 0; rr < 4; ++rr) cm = fmaxf(cm, acc[m][n][rr]);
      red[q * 4 + kb][p * 64 + n * 16 + rl] = cm;
    }
    __syncthreads();
    if (t < 128) {
      float m = red[0][t];
      #pragma unroll
      for (int rr = 1; rr < 8; ++rr) m = fmaxf(m, red[rr][t]);
      m += bias[n0 + t];
      int g = g0 + ((zc + m0) >> 10);
      atomicMax(&pooled[(size_t)g * 512 + n0 + t], encf(m));
    }
  }
}

// ---------------- head: per graph, lrelu(pooled@Wm1+bm1)@Wm2+bm2 ----------------
__global__ __launch_bounds__(256) void head_kernel(const unsigned* __restrict__ pooled,
                                                   const float* __restrict__ Wm1,
                                                   const float* __restrict__ bm1,
                                                   const float* __restrict__ Wm2,
                                                   const float* __restrict__ bm2,
                                                   float* __restrict__ out) {
  __shared__ float ps[512];
  __shared__ float hs[256];
  int b = blockIdx.x;
  int t = threadIdx.x;
  for (int l = t; l < 512; l += 256) ps[l] = decf(pooled[(size_t)b * 512 + l]);
  __syncthreads();
  float acc = bm1[t];
  for (int f = 0; f < 512; ++f) acc += ps[f] * Wm1[f * 256 + t];
  hs[t] = lrelu(acc);
  __syncthreads();
  if (t < 3) {
    float y = bm2[t];
    for (int f = 0; f < 256; ++f) y += hs[f] * Wm2[f * 3 + t];
    out[b * 3 + t] = y;
  }
}

static inline size_t al256(size_t v) { return (v + 255) & ~(size_t)255; }

extern "C" void kernel_launch(void* const* d_in, const int* in_sizes, int n_in,
                              void* d_out, int out_size, void* d_ws, size_t ws_size,
                              hipStream_t stream) {
  (void)in_sizes; (void)n_in; (void)out_size;
  const float* x    = (const float*)d_in[0];
  const float* pos  = (const float*)d_in[1];
  const float* tq   = (const float*)d_in[2];
  // d_in[3] = batch (uniform & sorted; unused)
  const float* W1   = (const float*)d_in[4];
  const float* b1   = (const float*)d_in[5];
  const float* W2   = (const float*)d_in[6];
  const float* b2   = (const float*)d_in[7];
  const float* Wl1a = (const float*)d_in[8];
  const float* bl1a = (const float*)d_in[9];
  const float* Wl1b = (const float*)d_in[10];
  const float* bl1b = (const float*)d_in[11];
  const float* Wm1  = (const float*)d_in[12];
  const float* bm1  = (const float*)d_in[13];
  const float* Wm2  = (const float*)d_in[14];
  const float* bm2  = (const float*)d_in[15];
  float* out = (float*)d_out;

  // ---- pick largest graph-chunk G whose workspace fits ----
  auto calc = [&](int G, size_t& hcB, size_t& hHB, size_t& uniB, size_t& wB) -> size_t {
    size_t M = (size_t)G * Nn;
    hcB = al256(M * 384 * 4);        // f32 hc (6 slots [M][64])
    hHB = al256(M * 384 * 2);        // bf16 hi (and lo) copies
    size_t convS = al256(M * 5 * 4) + 2 * al256(M * 64 * 4) +
                   al256(M * 4) + al256(M * Kk * 4);
    size_t Mz = M < 16384 ? M : 16384;
    size_t zB = 2 * al256(Mz * 512 * 2);  // zH + zL bf16
    uniB = convS > zB ? convS : zB;
    wB = 2 * al256((size_t)512 * 384 * 2) + 2 * al256((size_t)512 * 512 * 2);
    return hcB + 2 * hHB + uniB + al256((size_t)Bg * 512 * 4) + wB + 1024;
  };
  int G = 64;
  size_t hcB = 0, hHB = 0, uniB = 0, wB = 0;
  while (G > 1 && calc(G, hcB, hHB, uniB, wB) > ws_size) G >>= 1;
  calc(G, hcB, hHB, uniB, wB);
  const int M = G * Nn;
  const int Mz = M < 16384 ? M : 16384;

  char* w = (char*)d_ws;
  float*    hc  = (float*)w;
  short*    hH  = (short*)(w + hcB);
  short*    hL  = (short*)(w + hcB + hHB);
  char*     uni = w + hcB + 2 * hHB;
  float*    xx  = (float*)uni;
  float*    U   = (float*)(uni + al256((size_t)M * 5 * 4));
  float*    V   = (float*)((char*)U + al256((size_t)M * 64 * 4));
  float*    sqn = (float*)((char*)V + al256((size_t)M * 64 * 4));
  int*      idx = (int*)((char*)sqn + al256((size_t)M * 4));
  short*    zH  = (short*)uni;                               // MLP phase aliases conv scratch
  short*    zL  = (short*)(uni + al256((size_t)Mz * 512 * 2));
  unsigned* pooled = (unsigned*)(uni + uniB);
  short*    WHa = (short*)((char*)pooled + al256((size_t)Bg * 512 * 4));
  short*    WLa = WHa + (size_t)512 * 384;
  short*    WHb = (short*)((char*)WHa + 2 * al256((size_t)512 * 384 * 2));
  short*    WLb = WHb + (size_t)512 * 512;

  wprep<384><<<(384 * 512) / 256, 256, 0, stream>>>(Wl1a, WHa, WLa);
  wprep<512><<<(512 * 512) / 256, 256, 0, stream>>>(Wl1b, WHb, WLb);
  pooled_init<<<(Bg * 512) / 256, 256, 0, stream>>>(pooled);

  for (int g0 = 0; g0 < Bg; g0 += G) {
    build_xx<<<M / 256, 256, 0, stream>>>(x, pos, tq, xx, g0 * Nn);

    // conv1 (F=5, W1) -> slot 0
    uv_kernel<5><<<M / 16, 256, 0, stream>>>(xx, W1, U, V);
    sq_kernel<5><<<M / 4, 256, 0, stream>>>(xx, sqn);
    knn_kernel<5><<<dim3(Nn / 64, G), 256, 0, stream>>>(xx, sqn, idx);
    agg_kernel<<<M / 64, 256, 0, stream>>>(U, V, idx, b1, hc, hH, hL);

    // conv2..6 (F=64, shared W2) -> slots 1..5
    for (int c = 1; c < 6; ++c) {
      const float* hin = hc + (size_t)(c - 1) * M * 64;
      uv_kernel<64><<<M / 16, 256, 0, stream>>>(hin, W2, U, V);
      sq_kernel<64><<<M / 4, 256, 0, stream>>>(hin, sqn);
      knn_kernel<64><<<dim3(Nn / 64, G), 256, 0, stream>>>(hin, sqn, idx);
      agg_kernel<<<M / 64, 256, 0, stream>>>(U, V, idx, b2,
                                             hc + (size_t)c * M * 64,
                                             hH + (size_t)c * M * 64,
                                             hL + (size_t)c * M * 64);
    }

    // MLP over this chunk's rows, z-chunked
    for (int zc = 0; zc < M; zc += Mz) {
      mfma_gemm<0><<<dim3(4, Mz / 128), 256, 0, stream>>>(hH, hL, WHa, WLa, bl1a,
                                                          zH, zL, nullptr, M, zc, 0);
      mfma_gemm<1><<<dim3(4, Mz / 128), 256, 0, stream>>>(zH, zL, WHb, WLb, bl1b,
                                                          nullptr, nullptr, pooled, Mz, zc, g0);
    }
  }

  head_kernel<<<Bg, 256, 0, stream>>>(pooled, Wm1, bm1, Wm2, bm2, out);
}

// Round 9
// 1991.776 us; speedup vs baseline: 3.8329x; 1.2186x over previous
//
#include <hip/hip_runtime.h>
#include <cstdint>
#include <cstddef>

constexpr int Bg = 64;     // graphs
constexpr int Nn = 1024;   // nodes per graph
constexpr int Kk = 10;     // kNN neighbors
constexpr int BN = Bg * Nn;
#define SLOPE 0.01f

typedef __attribute__((ext_vector_type(8))) short s16x8;
typedef __attribute__((ext_vector_type(4))) float f32x4;

__device__ __forceinline__ float lrelu(float v) { return v >= 0.f ? v : SLOPE * v; }

// order-preserving float -> uint encoding
__device__ __forceinline__ unsigned encf(float f) {
  unsigned u = __float_as_uint(f);
  return (u & 0x80000000u) ? ~u : (u | 0x80000000u);
}
__device__ __forceinline__ float decf(unsigned e) {
  unsigned u = (e & 0x80000000u) ? (e & 0x7fffffffu) : ~e;
  return __uint_as_float(u);
}
// f32 -> bf16 (RNE) and back
__device__ __forceinline__ unsigned short f2bf(float f) {
  unsigned u = __float_as_uint(f);
  return (unsigned short)((u + 0x7FFFu + ((u >> 16) & 1u)) >> 16);
}
__device__ __forceinline__ float bf2f(unsigned short h) {
  return __uint_as_float(((unsigned)h) << 16);
}

__device__ __forceinline__ f32x4 mfma16(s16x8 a, s16x8 b, f32x4 c) {
  return __builtin_amdgcn_mfma_f32_16x16x32_bf16(a, b, c, 0, 0, 0);
}

__global__ __launch_bounds__(256) void pooled_init(unsigned* __restrict__ p) {
  p[blockIdx.x * 256 + threadIdx.x] = 0u;
}

// ---------------- build xx = [tq, x, pos] ----------------
__global__ __launch_bounds__(256) void build_xx(const float* __restrict__ x,
                                                const float* __restrict__ pos,
                                                const float* __restrict__ tq,
                                                float* __restrict__ xx, int rowoff) {
  int n = blockIdx.x * 256 + threadIdx.x;
  int g = rowoff + n;
  xx[n * 5 + 0] = tq[g];
  xx[n * 5 + 1] = x[g];
  xx[n * 5 + 2] = pos[g * 3 + 0];
  xx[n * 5 + 3] = pos[g * 3 + 1];
  xx[n * 5 + 4] = pos[g * 3 + 2];
}

// ---------------- weight prep: W[K][512] f32 -> WH/WL [512][K] bf16 ----------------
template <int K>
__global__ __launch_bounds__(256) void wprep(const float* __restrict__ W,
                                             short* __restrict__ WH,
                                             short* __restrict__ WL) {
  int idx = blockIdx.x * 256 + threadIdx.x;
  int k = idx >> 9, n = idx & 511;
  float v = W[idx];
  unsigned short h = f2bf(v);
  unsigned short lo = f2bf(v - bf2f(h));
  WH[(size_t)n * K + k] = (short)h;
  WL[(size_t)n * K + k] = (short)lo;
}

// ---------------- U = h @ (Wt - Wb), V = h @ Wb ----------------
template <int F>
__global__ __launch_bounds__(256) void uv_kernel(const float* __restrict__ h,
                                                 const float* __restrict__ W,  // [2F][64]
                                                 float* __restrict__ U,
                                                 float* __restrict__ V) {
  __shared__ float Ws[2 * F * 64];
  __shared__ float hs[16 * F];
  const int t = threadIdx.x;
  const int n0 = blockIdx.x * 16;
  for (int l = t; l < 2 * F * 64; l += 256) Ws[l] = W[l];
  for (int l = t; l < 16 * F; l += 256) hs[l] = h[(size_t)n0 * F + l];
  __syncthreads();
  for (int l = t; l < F * 64; l += 256) Ws[l] = Ws[l] - Ws[F * 64 + l];
  __syncthreads();
  const int o = t & 63;
  #pragma unroll
  for (int g4 = 0; g4 < 16; g4 += 4) {
    const int g = g4 + (t >> 6);
    float u = 0.f, v = 0.f;
    for (int f = 0; f < F; ++f) {
      float hv = hs[g * F + f];
      u += hv * Ws[f * 64 + o];
      v += hv * Ws[F * 64 + f * 64 + o];
    }
    U[(size_t)(n0 + g) * 64 + o] = u;
    V[(size_t)(n0 + g) * 64 + o] = v;
  }
}

// ---------------- sq[n] = sum_f h[n][f]^2 ----------------
template <int F>
__global__ __launch_bounds__(256) void sq_kernel(const float* __restrict__ h,
                                                 float* __restrict__ sqn) {
  int n = blockIdx.x * 4 + (threadIdx.x >> 6);
  int f = threadIdx.x & 63;
  float v = 0.f;
  if (f < F) v = h[(size_t)n * F + f];
  v *= v;
  #pragma unroll
  for (int off = 32; off > 0; off >>= 1) v += __shfl_down(v, off, 64);
  if (f == 0) sqn[n] = v;
}

// Branchless sorted top-10 (d,j) ladder; strict-< keeps incumbent on ties,
// ascending-j insertion order -> exact (d,j) lexicographic semantics.
#define LADDER_STATE                                                                     \
  float bd0 = INFINITY, bd1 = INFINITY, bd2 = INFINITY, bd3 = INFINITY, bd4 = INFINITY,  \
        bd5 = INFINITY, bd6 = INFINITY, bd7 = INFINITY, bd8 = INFINITY, bd9 = INFINITY;  \
  int bj0 = 0x7fffffff, bj1 = 0x7fffffff, bj2 = 0x7fffffff, bj3 = 0x7fffffff,            \
      bj4 = 0x7fffffff, bj5 = 0x7fffffff, bj6 = 0x7fffffff, bj7 = 0x7fffffff,            \
      bj8 = 0x7fffffff, bj9 = 0x7fffffff;

#define LADDER_INS                                                                        \
  auto ins = [&](float kd, int kj) {                                                      \
    bool m9 = kd < bd9; float t9d = m9 ? kd : bd9; int t9j = m9 ? kj : bj9;               \
    bool x9 = t9d < bd8; bd9 = x9 ? bd8 : t9d; bj9 = x9 ? bj8 : t9j;                      \
    bool m8 = kd < bd8; float t8d = m8 ? kd : bd8; int t8j = m8 ? kj : bj8;               \
    bool x8 = t8d < bd7; bd8 = x8 ? bd7 : t8d; bj8 = x8 ? bj7 : t8j;                      \
    bool m7 = kd < bd7; float t7d = m7 ? kd : bd7; int t7j = m7 ? kj : bj7;               \
    bool x7 = t7d < bd6; bd7 = x7 ? bd6 : t7d; bj7 = x7 ? bj6 : t7j;                      \
    bool m6 = kd < bd6; float t6d = m6 ? kd : bd6; int t6j = m6 ? kj : bj6;               \
    bool x6 = t6d < bd5; bd6 = x6 ? bd5 : t6d; bj6 = x6 ? bj5 : t6j;                      \
    bool m5 = kd < bd5; float t5d = m5 ? kd : bd5; int t5j = m5 ? kj : bj5;               \
    bool x5 = t5d < bd4; bd5 = x5 ? bd4 : t5d; bj5 = x5 ? bj4 : t5j;                      \
    bool m4 = kd < bd4; float t4d = m4 ? kd : bd4; int t4j = m4 ? kj : bj4;               \
    bool x4 = t4d < bd3; bd4 = x4 ? bd3 : t4d; bj4 = x4 ? bj3 : t4j;                      \
    bool m3 = kd < bd3; float t3d = m3 ? kd : bd3; int t3j = m3 ? kj : bj3;               \
    bool x3 = t3d < bd2; bd3 = x3 ? bd2 : t3d; bj3 = x3 ? bj2 : t3j;                      \
    bool m2 = kd < bd2; float t2d = m2 ? kd : bd2; int t2j = m2 ? kj : bj2;               \
    bool x2 = t2d < bd1; bd2 = x2 ? bd1 : t2d; bj2 = x2 ? bj1 : t2j;                      \
    bool m1 = kd < bd1; float t1d = m1 ? kd : bd1; int t1j = m1 ? kj : bj1;               \
    bool x1 = t1d < bd0; bd1 = x1 ? bd0 : t1d; bj1 = x1 ? bj0 : t1j;                      \
    bool m0 = kd < bd0; bd0 = m0 ? kd : bd0; bj0 = m0 ? kj : bj0;                         \
  };

#define FMA16(av, bv)                                                        \
  do {                                                                       \
    acc[0][0] += av.x * bv.x; acc[0][1] += av.x * bv.y;                      \
    acc[0][2] += av.x * bv.z; acc[0][3] += av.x * bv.w;                      \
    acc[1][0] += av.y * bv.x; acc[1][1] += av.y * bv.y;                      \
    acc[1][2] += av.y * bv.z; acc[1][3] += av.y * bv.w;                      \
    acc[2][0] += av.z * bv.x; acc[2][1] += av.z * bv.y;                      \
    acc[2][2] += av.z * bv.z; acc[2][3] += av.z * bv.w;                      \
    acc[3][0] += av.w * bv.x; acc[3][1] += av.w * bv.y;                      \
    acc[3][2] += av.w * bv.z; acc[3][3] += av.w * bv.w;                      \
  } while (0)

// ---------------- kNN (F=5, fp32 VALU path; round-8 proven) ----------------
template <int F>
__global__ __launch_bounds__(256) void knn_kernel(const float* __restrict__ h,
                                                  const float* __restrict__ sqn,
                                                  int* __restrict__ idxout) {
  constexpr int IPB = 64;
  constexpr int TJ = 64;
  constexpr int LDA = 68;
  constexpr int LDD = 65;
  constexpr int LDM = 41;
  constexpr int UNI = (IPB * LDM * 2 > TJ * LDA) ? IPB * LDM * 2 : TJ * LDA;
  __shared__ float As[F][LDA];
  __shared__ float uni[UNI];
  __shared__ float sqt[TJ];
  float* Bs = uni;
  float* D  = uni;
  float* md = uni;
  int*   mi = (int*)(uni + IPB * LDM);

  const int b = blockIdx.y;
  const int i0 = blockIdx.x * IPB;
  const int t = threadIdx.x;
  const int tx = t & 15, ty = t >> 4;
  const int gbase = b * Nn;
  const int r = t & 63;
  const int s = t >> 6;

  for (int l = t; l < IPB * F; l += 256) {
    int row = l / F, f = l % F;
    As[f][row] = h[(size_t)(gbase + i0 + row) * F + f];
  }

  LADDER_STATE
  LADDER_INS

  for (int jt = 0; jt < Nn; jt += TJ) {
    __syncthreads();
    for (int l = t; l < TJ * F; l += 256) {
      int row = l / F, f = l % F;
      Bs[f * LDA + row] = h[(size_t)(gbase + jt + row) * F + f];
    }
    if (t < TJ) sqt[t] = sqn[gbase + jt + t];
    __syncthreads();

    float acc[4][4] = {{0.f, 0.f, 0.f, 0.f}, {0.f, 0.f, 0.f, 0.f},
                       {0.f, 0.f, 0.f, 0.f}, {0.f, 0.f, 0.f, 0.f}};
    #pragma unroll
    for (int f = 0; f < F; ++f) {
      float4 av = *(const float4*)&As[f][ty * 4];
      float4 bv = *(const float4*)(Bs + f * LDA + tx * 4);
      FMA16(av, bv);
    }
    __syncthreads();

    float4 sj = *(const float4*)&sqt[tx * 4];
    #pragma unroll
    for (int ii = 0; ii < 4; ++ii) {
      float* dr = D + (ty * 4 + ii) * LDD + tx * 4;
      dr[0] = sj.x - 2.f * acc[ii][0];
      dr[1] = sj.y - 2.f * acc[ii][1];
      dr[2] = sj.z - 2.f * acc[ii][2];
      dr[3] = sj.w - 2.f * acc[ii][3];
    }
    __syncthreads();

    {
      const float* drow = D + r * LDD + s * 16;
      float dv[16];
      #pragma unroll
      for (int qq = 0; qq < 16; ++qq) dv[qq] = drow[qq];
      #pragma unroll
      for (int qq = 0; qq < 16; ++qq) ins(dv[qq], jt + s * 16 + qq);
    }
  }

  __syncthreads();
  {
    float* rd = md + r * LDM + s * 10;
    int*   ri = mi + r * LDM + s * 10;
    rd[0] = bd0; rd[1] = bd1; rd[2] = bd2; rd[3] = bd3; rd[4] = bd4;
    rd[5] = bd5; rd[6] = bd6; rd[7] = bd7; rd[8] = bd8; rd[9] = bd9;
    ri[0] = bj0; ri[1] = bj1; ri[2] = bj2; ri[3] = bj3; ri[4] = bj4;
    ri[5] = bj5; ri[6] = bj6; ri[7] = bj7; ri[8] = bj8; ri[9] = bj9;
  }
  __syncthreads();
  if (s == 0) {
    float* rd = md + r * LDM;
    int*   ri = mi + r * LDM;
    #pragma unroll 1
    for (int q = 0; q < Kk; ++q) {
      float best = INFINITY;
      int besti = 0x7fffffff, bslot = 0;
      #pragma unroll 1
      for (int e = 0; e < 40; ++e) {
        float d = rd[e];
        int ix = ri[e];
        bool g = (d < best) || (d == best && ix < besti);
        if (g) { best = d; besti = ix; bslot = e; }
      }
      rd[bslot] = INFINITY;
      idxout[(size_t)(gbase + i0 + r) * Kk + q] = besti;
    }
  }
}

// ---------------- kNN (F=64): MFMA bf16x2 4-term distances + ladder ----------------
// A-fragments (i-rows) held in registers for the whole kernel; B-tiles staged
// bf16 hi/lo in LDS; D = sqt[j] - 2*dot via verified 16x16x32 C/D layout.
__global__ __launch_bounds__(256) void knn64_mfma(const short* __restrict__ hH,
                                                  const short* __restrict__ hL,
                                                  const float* __restrict__ sqn,
                                                  int* __restrict__ idxout) {
  constexpr int LDB = 72;   // shorts; 144B rows (16B-aligned)
  constexpr int LDD = 65;   // floats
  constexpr int LDM = 41;
  __shared__ short BHs[64 * LDB], BLs[64 * LDB];
  __shared__ float uni[64 * LDM * 2];   // D (64*65) aliases merge (64*41*2)
  __shared__ float sqt[64];
  float* D  = uni;
  float* md = uni;
  int*   mi = (int*)(uni + 64 * LDM);

  const int b = blockIdx.y;
  const int i0 = blockIdx.x * 64;
  const int t = threadIdx.x;
  const int w = t >> 6, l = t & 63;
  const int rl = l & 15, kb = l >> 4;
  const int gbase = b * Nn;

  // ---- A fragments in registers: wave w owns i-rows w*16..w*16+15 ----
  s16x8 aH0, aH1, aL0, aL1;
  {
    const size_t ar = (size_t)(gbase + i0 + w * 16 + rl) * 64;
    aH0 = *(const s16x8*)&hH[ar + kb * 8];
    aH1 = *(const s16x8*)&hH[ar + 32 + kb * 8];
    aL0 = *(const s16x8*)&hL[ar + kb * 8];
    aL1 = *(const s16x8*)&hL[ar + 32 + kb * 8];
  }

  LADDER_STATE
  LADDER_INS

  // ---- B-tile prefetch (each thread: row l, 16B chunks w and w+4) ----
  uint4 pH0, pH1, pL0, pL1;
  {
    const size_t rb = (size_t)(gbase + l) * 64;
    pH0 = *(const uint4*)&hH[rb + w * 8];
    pH1 = *(const uint4*)&hH[rb + (w + 4) * 8];
    pL0 = *(const uint4*)&hL[rb + w * 8];
    pL1 = *(const uint4*)&hL[rb + (w + 4) * 8];
  }

  for (int jt = 0; jt < Nn; jt += 64) {
    __syncthreads();  // prev selection done reading D; prev MFMA done reading B
    *(uint4*)&BHs[l * LDB + w * 8]       = pH0;
    *(uint4*)&BHs[l * LDB + (w + 4) * 8] = pH1;
    *(uint4*)&BLs[l * LDB + w * 8]       = pL0;
    *(uint4*)&BLs[l * LDB + (w + 4) * 8] = pL1;
    if (t < 64) sqt[t] = sqn[gbase + jt + t];
    if (jt + 64 < Nn) {
      const size_t rb = (size_t)(gbase + jt + 64 + l) * 64;
      pH0 = *(const uint4*)&hH[rb + w * 8];
      pH1 = *(const uint4*)&hH[rb + (w + 4) * 8];
      pL0 = *(const uint4*)&hL[rb + w * 8];
      pL1 = *(const uint4*)&hL[rb + (w + 4) * 8];
    }
    __syncthreads();

    // ---- MFMA: acc[cg] = dot(i-rows of wave w, j-cols cg*16..cg*16+15) ----
    f32x4 acc[4];
    #pragma unroll
    for (int cg = 0; cg < 4; ++cg) acc[cg] = (f32x4){0.f, 0.f, 0.f, 0.f};
    #pragma unroll
    for (int cg = 0; cg < 4; ++cg) {
      const int co = (cg * 16 + rl) * LDB;
      s16x8 bh0 = *(const s16x8*)&BHs[co + kb * 8];
      s16x8 bh1 = *(const s16x8*)&BHs[co + 32 + kb * 8];
      s16x8 bl0 = *(const s16x8*)&BLs[co + kb * 8];
      s16x8 bl1 = *(const s16x8*)&BLs[co + 32 + kb * 8];
      acc[cg] = mfma16(aH0, bh0, acc[cg]);
      acc[cg] = mfma16(aH0, bl0, acc[cg]);
      acc[cg] = mfma16(aL0, bh0, acc[cg]);
      acc[cg] = mfma16(aL0, bl0, acc[cg]);
      acc[cg] = mfma16(aH1, bh1, acc[cg]);
      acc[cg] = mfma16(aH1, bl1, acc[cg]);
      acc[cg] = mfma16(aL1, bh1, acc[cg]);
      acc[cg] = mfma16(aL1, bl1, acc[cg]);
    }

    // ---- D write: row = w*16 + kb*4 + rr, col = cg*16 + rl ----
    #pragma unroll
    for (int cg = 0; cg < 4; ++cg) {
      float sj = sqt[cg * 16 + rl];
      float* dp = D + (w * 16 + kb * 4) * LDD + cg * 16 + rl;
      dp[0 * LDD] = sj - 2.f * acc[cg][0];
      dp[1 * LDD] = sj - 2.f * acc[cg][1];
      dp[2 * LDD] = sj - 2.f * acc[cg][2];
      dp[3 * LDD] = sj - 2.f * acc[cg][3];
    }
    __syncthreads();

    // ---- selection: lane l = row l, subset w ----
    {
      const float* drow = D + l * LDD + w * 16;
      float dv[16];
      #pragma unroll
      for (int qq = 0; qq < 16; ++qq) dv[qq] = drow[qq];
      #pragma unroll
      for (int qq = 0; qq < 16; ++qq) ins(dv[qq], jt + w * 16 + qq);
    }
  }

  // ---- merge 4 sorted-10s per row -> top-10 ----
  __syncthreads();
  {
    float* rd = md + l * LDM + w * 10;
    int*   ri = mi + l * LDM + w * 10;
    rd[0] = bd0; rd[1] = bd1; rd[2] = bd2; rd[3] = bd3; rd[4] = bd4;
    rd[5] = bd5; rd[6] = bd6; rd[7] = bd7; rd[8] = bd8; rd[9] = bd9;
    ri[0] = bj0; ri[1] = bj1; ri[2] = bj2; ri[3] = bj3; ri[4] = bj4;
    ri[5] = bj5; ri[6] = bj6; ri[7] = bj7; ri[8] = bj8; ri[9] = bj9;
  }
  __syncthreads();
  if (w == 0) {
    float* rd = md + l * LDM;
    int*   ri = mi + l * LDM;
    #pragma unroll 1
    for (int q = 0; q < Kk; ++q) {
      float best = INFINITY;
      int besti = 0x7fffffff, bslot = 0;
      #pragma unroll 1
      for (int e = 0; e < 40; ++e) {
        float d = rd[e];
        int ix = ri[e];
        bool g = (d < best) || (d == best && ix < besti);
        if (g) { best = d; besti = ix; bslot = e; }
      }
      rd[bslot] = INFINITY;
      idxout[(size_t)(gbase + i0 + l) * Kk + q] = besti;
    }
  }
}

// ---------------- h_out[i] = sum_k lrelu(U[i] + V[j_k] + b); also bf16 hi/lo ----------------
__global__ __launch_bounds__(256) void agg_kernel(const float* __restrict__ U,
                                                  const float* __restrict__ V,
                                                  const int* __restrict__ idx,
                                                  const float* __restrict__ bias,
                                                  float* __restrict__ hout,
                                                  short* __restrict__ hH,
                                                  short* __restrict__ hL) {
  int t = blockIdx.x * 256 + threadIdx.x;
  int n = t >> 2;
  int o0 = (t & 3) * 16;
  int gb = n & ~(Nn - 1);
  float4 u[4], bb[4], acc[4];
  #pragma unroll
  for (int q = 0; q < 4; ++q) {
    u[q] = *(const float4*)&U[(size_t)n * 64 + o0 + q * 4];
    bb[q] = *(const float4*)&bias[o0 + q * 4];
    acc[q] = make_float4(0.f, 0.f, 0.f, 0.f);
  }
  #pragma unroll
  for (int k = 0; k < Kk; ++k) {
    int j = gb + idx[n * Kk + k];
    #pragma unroll
    for (int q = 0; q < 4; ++q) {
      float4 v = *(const float4*)&V[(size_t)j * 64 + o0 + q * 4];
      acc[q].x += lrelu(u[q].x + v.x + bb[q].x);
      acc[q].y += lrelu(u[q].y + v.y + bb[q].y);
      acc[q].z += lrelu(u[q].z + v.z + bb[q].z);
      acc[q].w += lrelu(u[q].w + v.w + bb[q].w);
    }
  }
  #pragma unroll
  for (int q = 0; q < 4; ++q) {
    *(float4*)&hout[(size_t)n * 64 + o0 + q * 4] = acc[q];
    ushort4 hv, lv;
    hv.x = f2bf(acc[q].x); lv.x = f2bf(acc[q].x - bf2f(hv.x));
    hv.y = f2bf(acc[q].y); lv.y = f2bf(acc[q].y - bf2f(hv.y));
    hv.z = f2bf(acc[q].z); lv.z = f2bf(acc[q].z - bf2f(hv.z));
    hv.w = f2bf(acc[q].w); lv.w = f2bf(acc[q].w - bf2f(hv.w));
    *(ushort4*)&hH[(size_t)n * 64 + o0 + q * 4] = hv;
    *(ushort4*)&hL[(size_t)n * 64 + o0 + q * 4] = lv;
  }
}

// ---------------- MFMA bf16x2 (hi/lo, 3-term) GEMM, 128x128 tile ----------------
template <int MODE>
__global__ __launch_bounds__(256) void mfma_gemm(const short* __restrict__ AH,
                                                 const short* __restrict__ AL,
                                                 const short* __restrict__ BH,
                                                 const short* __restrict__ BL,
                                                 const float* __restrict__ bias,
                                                 short* __restrict__ outH,
                                                 short* __restrict__ outL,
                                                 unsigned* __restrict__ pooled,
                                                 int Msl, int zc, int g0) {
  constexpr int Kdim = (MODE == 0) ? 384 : 512;
  __shared__ short AHs[128][40], ALs[128][40], BHs[128][40], BLs[128][40];
  __shared__ float red[8][132];
  const int t = threadIdx.x;
  const int m0 = blockIdx.y * 128, n0 = blockIdx.x * 128;
  const int w = t >> 6, l = t & 63;
  const int q = w >> 1, p = w & 1, rl = l & 15, kb = l >> 4;
  const int srow = t >> 1, sc = (t & 1) * 16;

  f32x4 acc[4][4];
  #pragma unroll
  for (int m = 0; m < 4; ++m)
    #pragma unroll
    for (int n = 0; n < 4; ++n) acc[m][n] = (f32x4){0.f, 0.f, 0.f, 0.f};

  for (int k0 = 0; k0 < Kdim; k0 += 32) {
    size_t aoff, boff;
    if constexpr (MODE == 0)
      aoff = ((size_t)(k0 >> 6) * Msl + zc + m0 + srow) * 64 + (k0 & 63) + sc;
    else
      aoff = (size_t)(m0 + srow) * 512 + k0 + sc;
    boff = (size_t)(n0 + srow) * Kdim + k0 + sc;
    __syncthreads();
    *(uint4*)&AHs[srow][sc]     = *(const uint4*)(AH + aoff);
    *(uint4*)&AHs[srow][sc + 8] = *(const uint4*)(AH + aoff + 8);
    *(uint4*)&ALs[srow][sc]     = *(const uint4*)(AL + aoff);
    *(uint4*)&ALs[srow][sc + 8] = *(const uint4*)(AL + aoff + 8);
    *(uint4*)&BHs[srow][sc]     = *(const uint4*)(BH + boff);
    *(uint4*)&BHs[srow][sc + 8] = *(const uint4*)(BH + boff + 8);
    *(uint4*)&BLs[srow][sc]     = *(const uint4*)(BL + boff);
    *(uint4*)&BLs[srow][sc + 8] = *(const uint4*)(BL + boff + 8);
    __syncthreads();

    s16x8 aH[4], aL[4], bH[4], bL[4];
    #pragma unroll
    for (int m = 0; m < 4; ++m) {
      aH[m] = *(const s16x8*)&AHs[q * 64 + m * 16 + rl][kb * 8];
      aL[m] = *(const s16x8*)&ALs[q * 64 + m * 16 + rl][kb * 8];
    }
    #pragma unroll
    for (int n = 0; n < 4; ++n) {
      bH[n] = *(const s16x8*)&BHs[p * 64 + n * 16 + rl][kb * 8];
      bL[n] = *(const s16x8*)&BLs[p * 64 + n * 16 + rl][kb * 8];
    }
    #pragma unroll
    for (int m = 0; m < 4; ++m)
      #pragma unroll
      for (int n = 0; n < 4; ++n) {
        acc[m][n] = mfma16(aH[m], bH[n], acc[m][n]);
        acc[m][n] = mfma16(aH[m], bL[n], acc[m][n]);
        acc[m][n] = mfma16(aL[m], bH[n], acc[m][n]);
      }
  }

  if constexpr (MODE == 0) {
    #pragma unroll
    for (int n = 0; n < 4; ++n) {
      const int col = n0 + p * 64 + n * 16 + rl;
      const float bv = bias[col];
      #pragma unroll
      for (int m = 0; m < 4; ++m) {
        #pragma unroll
        for (int rr = 0; rr < 4; ++rr) {
          int row = m0 + q * 64 + m * 16 + kb * 4 + rr;
          float v = lrelu(acc[m][n][rr] + bv);
          unsigned short hv = f2bf(v);
          unsigned short lv = f2bf(v - bf2f(hv));
          outH[(size_t)row * 512 + col] = (short)hv;
          outL[(size_t)row * 512 + col] = (short)lv;
        }
      }
    }
  } else {
    #pragma unroll
    for (int n = 0; n < 4; ++n) {
      float cm = acc[0][n][0];
      #pragma unroll
      for (int m = 0; m < 4; ++m)
        #pragma unroll
        for (int rr = 0; rr < 4; ++rr) cm = fmaxf(cm, acc[m][n][rr]);
      red[q * 4 + kb][p * 64 + n * 16 + rl] = cm;
    }
    __syncthreads();
    if (t < 128) {
      float m = red[0][t];
      #pragma unroll
      for (int rr = 1; rr < 8; ++rr) m = fmaxf(m, red[rr][t]);
      m += bias[n0 + t];
      int g = g0 + ((zc + m0) >> 10);
      atomicMax(&pooled[(size_t)g * 512 + n0 + t], encf(m));
    }
  }
}

// ---------------- head: per graph, lrelu(pooled@Wm1+bm1)@Wm2+bm2 ----------------
__global__ __launch_bounds__(256) void head_kernel(const unsigned* __restrict__ pooled,
                                                   const float* __restrict__ Wm1,
                                                   const float* __restrict__ bm1,
                                                   const float* __restrict__ Wm2,
                                                   const float* __restrict__ bm2,
                                                   float* __restrict__ out) {
  __shared__ float ps[512];
  __shared__ float hs[256];
  int b = blockIdx.x;
  int t = threadIdx.x;
  for (int l = t; l < 512; l += 256) ps[l] = decf(pooled[(size_t)b * 512 + l]);
  __syncthreads();
  float acc = bm1[t];
  for (int f = 0; f < 512; ++f) acc += ps[f] * Wm1[f * 256 + t];
  hs[t] = lrelu(acc);
  __syncthreads();
  if (t < 3) {
    float y = bm2[t];
    for (int f = 0; f < 256; ++f) y += hs[f] * Wm2[f * 3 + t];
    out[b * 3 + t] = y;
  }
}

static inline size_t al256(size_t v) { return (v + 255) & ~(size_t)255; }

extern "C" void kernel_launch(void* const* d_in, const int* in_sizes, int n_in,
                              void* d_out, int out_size, void* d_ws, size_t ws_size,
                              hipStream_t stream) {
  (void)in_sizes; (void)n_in; (void)out_size;
  const float* x    = (const float*)d_in[0];
  const float* pos  = (const float*)d_in[1];
  const float* tq   = (const float*)d_in[2];
  // d_in[3] = batch (uniform & sorted; unused)
  const float* W1   = (const float*)d_in[4];
  const float* b1   = (const float*)d_in[5];
  const float* W2   = (const float*)d_in[6];
  const float* b2   = (const float*)d_in[7];
  const float* Wl1a = (const float*)d_in[8];
  const float* bl1a = (const float*)d_in[9];
  const float* Wl1b = (const float*)d_in[10];
  const float* bl1b = (const float*)d_in[11];
  const float* Wm1  = (const float*)d_in[12];
  const float* bm1  = (const float*)d_in[13];
  const float* Wm2  = (const float*)d_in[14];
  const float* bm2  = (const float*)d_in[15];
  float* out = (float*)d_out;

  // ---- pick largest graph-chunk G whose workspace fits ----
  auto calc = [&](int G, size_t& hcB, size_t& hHB, size_t& uniB, size_t& wB) -> size_t {
    size_t M = (size_t)G * Nn;
    hcB = al256(M * 384 * 4);
    hHB = al256(M * 384 * 2);
    size_t convS = al256(M * 5 * 4) + 2 * al256(M * 64 * 4) +
                   al256(M * 4) + al256(M * Kk * 4);
    size_t Mz = M < 16384 ? M : 16384;
    size_t zB = 2 * al256(Mz * 512 * 2);
    uniB = convS > zB ? convS : zB;
    wB = 2 * al256((size_t)512 * 384 * 2) + 2 * al256((size_t)512 * 512 * 2);
    return hcB + 2 * hHB + uniB + al256((size_t)Bg * 512 * 4) + wB + 1024;
  };
  int G = 64;
  size_t hcB = 0, hHB = 0, uniB = 0, wB = 0;
  while (G > 1 && calc(G, hcB, hHB, uniB, wB) > ws_size) G >>= 1;
  calc(G, hcB, hHB, uniB, wB);
  const int M = G * Nn;
  const int Mz = M < 16384 ? M : 16384;

  char* w = (char*)d_ws;
  float*    hc  = (float*)w;
  short*    hH  = (short*)(w + hcB);
  short*    hL  = (short*)(w + hcB + hHB);
  char*     uni = w + hcB + 2 * hHB;
  float*    xx  = (float*)uni;
  float*    U   = (float*)(uni + al256((size_t)M * 5 * 4));
  float*    V   = (float*)((char*)U + al256((size_t)M * 64 * 4));
  float*    sqn = (float*)((char*)V + al256((size_t)M * 64 * 4));
  int*      idx = (int*)((char*)sqn + al256((size_t)M * 4));
  short*    zH  = (short*)uni;
  short*    zL  = (short*)(uni + al256((size_t)Mz * 512 * 2));
  unsigned* pooled = (unsigned*)(uni + uniB);
  short*    WHa = (short*)((char*)pooled + al256((size_t)Bg * 512 * 4));
  short*    WLa = WHa + (size_t)512 * 384;
  short*    WHb = (short*)((char*)WHa + 2 * al256((size_t)512 * 384 * 2));
  short*    WLb = WHb + (size_t)512 * 512;

  wprep<384><<<(384 * 512) / 256, 256, 0, stream>>>(Wl1a, WHa, WLa);
  wprep<512><<<(512 * 512) / 256, 256, 0, stream>>>(Wl1b, WHb, WLb);
  pooled_init<<<(Bg * 512) / 256, 256, 0, stream>>>(pooled);

  for (int g0 = 0; g0 < Bg; g0 += G) {
    build_xx<<<M / 256, 256, 0, stream>>>(x, pos, tq, xx, g0 * Nn);

    // conv1 (F=5, W1) -> slot 0
    uv_kernel<5><<<M / 16, 256, 0, stream>>>(xx, W1, U, V);
    sq_kernel<5><<<M / 4, 256, 0, stream>>>(xx, sqn);
    knn_kernel<5><<<dim3(Nn / 64, G), 256, 0, stream>>>(xx, sqn, idx);
    agg_kernel<<<M / 64, 256, 0, stream>>>(U, V, idx, b1, hc, hH, hL);

    // conv2..6 (F=64, shared W2) -> slots 1..5
    for (int c = 1; c < 6; ++c) {
      const float* hin = hc + (size_t)(c - 1) * M * 64;
      const short* hHin = hH + (size_t)(c - 1) * M * 64;
      const short* hLin = hL + (size_t)(c - 1) * M * 64;
      uv_kernel<64><<<M / 16, 256, 0, stream>>>(hin, W2, U, V);
      sq_kernel<64><<<M / 4, 256, 0, stream>>>(hin, sqn);
      knn64_mfma<<<dim3(Nn / 64, G), 256, 0, stream>>>(hHin, hLin, sqn, idx);
      agg_kernel<<<M / 64, 256, 0, stream>>>(U, V, idx, b2,
                                             hc + (size_t)c * M * 64,
                                             hH + (size_t)c * M * 64,
                                             hL + (size_t)c * M * 64);
    }

    // MLP over this chunk's rows, z-chunked
    for (int zc = 0; zc < M; zc += Mz) {
      mfma_gemm<0><<<dim3(4, Mz / 128), 256, 0, stream>>>(hH, hL, WHa, WLa, bl1a,
                                                          zH, zL, nullptr, M, zc, 0);
      mfma_gemm<1><<<dim3(4, Mz / 128), 256, 0, stream>>>(zH, zL, WHb, WLb, bl1b,
                                                          nullptr, nullptr, pooled, Mz, zc, g0);
    }
  }

  head_kernel<<<Bg, 256, 0, stream>>>(pooled, Wm1, bm1, Wm2, bm2, out);
}